// Round 4
// baseline (7983.555 us; speedup 1.0000x reference)
//
#include <hip/hip_runtime.h>

#define BB 32
#define DD 256
#define TT 1024
#define KK 8192

typedef __attribute__((ext_vector_type(16))) float f16v;

// ws layout:
//   byte 0      : double loss_acc
//   byte 64     : float Bf[K]      (32768 B)   np-pairwise ||e_k||^2
//   byte 32832  : float Af[B*T]    (131072 B)  np-pairwise ||z_n||^2
//   byte 163904 : int   idx_i[B*T] (131072 B)

// Bit-exact numpy pairwise_sum of x[i]^2, n=256 (two 128-blocks, 8 strided
// accumulators each, ((r0+r1)+(r2+r3))+((r4+r5)+(r6+r7)), halves added).
__device__ __forceinline__ float np_sq_sum256(const float* __restrict__ base, int stride) {
    float res[2];
    #pragma unroll
    for (int blk = 0; blk < 2; ++blk) {
        const int o = blk * 128;
        float r[8];
        #pragma unroll
        for (int j = 0; j < 8; ++j) {
            const float x = base[(o + j) * stride];
            r[j] = __fmul_rn(x, x);
        }
        for (int i = 8; i < 128; i += 8) {
            #pragma unroll
            for (int j = 0; j < 8; ++j) {
                const float x = base[(o + i + j) * stride];
                r[j] = __fadd_rn(r[j], __fmul_rn(x, x));
            }
        }
        res[blk] = __fadd_rn(__fadd_rn(__fadd_rn(r[0], r[1]), __fadd_rn(r[2], r[3])),
                             __fadd_rn(__fadd_rn(r[4], r[5]), __fadd_rn(r[6], r[7])));
    }
    return __fadd_rn(res[0], res[1]);
}

__global__ __launch_bounds__(256) void bsum_kernel(const float* __restrict__ emb,
                                                   float* __restrict__ Bf) {
    const int k = blockIdx.x * 256 + threadIdx.x;
    Bf[k] = np_sq_sum256(emb + (size_t)k * DD, 1);
}

__global__ __launch_bounds__(256) void asum_kernel(const float* __restrict__ z_e,
                                                   float* __restrict__ Af) {
    const int n = blockIdx.x * 256 + threadIdx.x;
    const int b = n >> 10, t = n & 1023;
    Af[n] = np_sq_sum256(z_e + ((size_t)b << 18) + t, TT);
}

// e-tile staging: step s -> k-group kg = s>>2 (64 codes), d-chunk c = s&3 (64 dims).
// Tile stored TRANSPOSED with +1 pad: buf[dd*65 + kk]  (dd = chunk-local d, kk = k-lane).
__device__ __forceinline__ void ldrows(const float* __restrict__ emb, int s, int tid,
                                       float4* g) {
    const int kg = s >> 2, c = s & 3;
    const int row = tid >> 4, c4 = tid & 15;
    const float* base = emb + (((size_t)(kg * 64 + row)) << 8) + c * 64 + c4 * 4;
    #pragma unroll
    for (int m = 0; m < 4; ++m)
        g[m] = *reinterpret_cast<const float4*>(base + ((size_t)(m * 16) << 8));
}

__device__ __forceinline__ void wrrows(float* __restrict__ buf, int tid, const float4* g) {
    const int row = tid >> 4, c4 = tid & 15;
    #pragma unroll
    for (int m = 0; m < 4; ++m) {
        buf[(c4 * 4 + 0) * 65 + row + 16 * m] = g[m].x;
        buf[(c4 * 4 + 1) * 65 + row + 16 * m] = g[m].y;
        buf[(c4 * 4 + 2) * 65 + row + 16 * m] = g[m].z;
        buf[(c4 * 4 + 3) * 65 + row + 16 * m] = g[m].w;
    }
}

// Scorer: block = 256 threads = 4 waves, 64 queries per block (16 per wave,
// wave-uniform); lane = code within the 64-wide k-group. z comes in via
// uniform s_load_dwordx16 (SGPR operand of v_fmac); e via 1 conflict-free
// ds_read_b32 per d. Per d per wave: 16 FMAs.
__global__ __launch_bounds__(256) void score4_kernel(
    const float* __restrict__ z_e, const float* __restrict__ emb,
    const float* __restrict__ Bf, const float* __restrict__ Af,
    float* __restrict__ out_idx, int* __restrict__ idx_i,
    double* __restrict__ loss_acc) {
    __shared__ float et[2][4160];      // 2 x 64 x 65 floats, 33.3 KiB

    const int tid  = threadIdx.x;
    const int lane = tid & 63;
    const int w    = __builtin_amdgcn_readfirstlane(tid >> 6);  // uniform wave id
    const int n0   = blockIdx.x * 64;
    const int b    = n0 >> 10, t0 = n0 & 1023;
    const int qb   = n0 + w * 16;      // this wave's 16 queries (uniform)

    const float* zb = z_e + ((size_t)b << 18) + (t0 + w * 16);  // + d*1024
    const f16v Av = *reinterpret_cast<const f16v*>(Af + qb);    // uniform 64B

    float acc[16], best[16];
    int bidx[16];
    #pragma unroll
    for (int j = 0; j < 16; ++j) { best[j] = 3.0e38f; bidx[j] = 0; }

    float4 g[4];
    ldrows(emb, 0, tid, g);
    wrrows(et[0], tid, g);
    __syncthreads();

    for (int s = 0; s < 512; ++s) {
        const int c = s & 3, kg = s >> 2;
        const int sn = (s < 511) ? s + 1 : 511;
        ldrows(emb, sn, tid, g);                 // prefetch next tile into regs

        if (c == 0) {
            #pragma unroll
            for (int j = 0; j < 16; ++j) acc[j] = 0.0f;
        }

        const float* zd  = zb + (size_t)(c * 64) * TT;   // uniform base
        const float* cur = et[s & 1];
        #pragma unroll 2
        for (int dd = 0; dd < 64; ++dd) {
            const float ev = cur[dd * 65 + lane];
            const f16v zv = *reinterpret_cast<const f16v*>(zd + (size_t)dd * TT);
            #pragma unroll
            for (int j = 0; j < 16; ++j) acc[j] = __fmaf_rn(zv[j], ev, acc[j]);
        }

        if (c == 3) {                             // k-group complete: fold argmin
            const int k = kg * 64 + lane;
            const float Bk = Bf[k];
            #pragma unroll
            for (int j = 0; j < 16; ++j) {
                const float t1   = __fadd_rn(Av[j], Bk);
                const float m2   = __fadd_rn(acc[j], acc[j]);
                const float dist = __fsub_rn(t1, m2);
                if (dist < best[j]) { best[j] = dist; bidx[j] = k; }
            }
        }

        wrrows(et[(s + 1) & 1], tid, g);         // commit prefetched tile
        __syncthreads();
    }

    // cross-lane argmin (64 lanes hold disjoint k residues)
    #pragma unroll
    for (int j = 0; j < 16; ++j) {
        float bb = best[j];
        int   bi = bidx[j];
        #pragma unroll
        for (int off = 1; off < 64; off <<= 1) {
            const float ob = __shfl_xor(bb, off);
            const int   oi = __shfl_xor(bi, off);
            if (ob < bb || (ob == bb && oi < bi)) { bb = ob; bi = oi; }
        }
        best[j] = bb; bidx[j] = bi;
    }
    if (lane == 0) {
        double lp = 0.0;
        #pragma unroll
        for (int j = 0; j < 16; ++j) {
            out_idx[qb + j] = (float)bidx[j];
            idx_i[qb + j]   = bidx[j];
            lp += (double)best[j];
        }
        atomicAdd(loss_acc, lp);
    }
}

__global__ __launch_bounds__(256) void gather_kernel(const float* __restrict__ emb,
                                                     const int* __restrict__ idx_i,
                                                     float* __restrict__ zq) {
    const int blk = blockIdx.x;
    const int b  = blk >> 4;
    const int t0 = (blk & 15) * 64;
    const int q  = threadIdx.x & 63;
    const int dc = threadIdx.x >> 6;
    const int n  = b * TT + t0 + q;
    const int k  = idx_i[n];
    const float4* erow = reinterpret_cast<const float4*>(emb + (size_t)k * DD + dc * 64);
    #pragma unroll
    for (int jj = 0; jj < 16; ++jj) {
        const float4 v = erow[jj];
        const int d = dc * 64 + jj * 4;
        zq[(size_t)(b * DD + d + 0) * TT + t0 + q] = v.x;
        zq[(size_t)(b * DD + d + 1) * TT + t0 + q] = v.y;
        zq[(size_t)(b * DD + d + 2) * TT + t0 + q] = v.z;
        zq[(size_t)(b * DD + d + 3) * TT + t0 + q] = v.w;
    }
}

__global__ void fin_kernel(const double* __restrict__ loss_acc,
                           float* __restrict__ out_loss) {
    out_loss[0] = (float)(loss_acc[0] * (1.0 / ((double)BB * DD * TT)));
}

extern "C" void kernel_launch(void* const* d_in, const int* in_sizes, int n_in,
                              void* d_out, int out_size, void* d_ws, size_t ws_size,
                              hipStream_t stream) {
    const float* z_e = (const float*)d_in[0];
    const float* emb = (const float*)d_in[1];

    float* out      = (float*)d_out;
    float* zq       = out;
    float* out_loss = out + (size_t)BB * DD * TT;
    float* out_idx  = out_loss + 1;

    double* loss_acc = (double*)d_ws;
    float*  Bf       = (float*)((char*)d_ws + 64);
    float*  Af       = (float*)((char*)d_ws + 64 + (size_t)KK * 4);
    int*    idx_i    = (int*)((char*)d_ws + 64 + (size_t)KK * 4 + (size_t)BB * TT * 4);

    hipMemsetAsync(d_ws, 0, 64, stream);
    bsum_kernel<<<KK / 256, 256, 0, stream>>>(emb, Bf);
    asum_kernel<<<(BB * TT) / 256, 256, 0, stream>>>(z_e, Af);
    score4_kernel<<<(BB * TT) / 64, 256, 0, stream>>>(z_e, emb, Bf, Af, out_idx, idx_i, loss_acc);
    gather_kernel<<<(BB * TT) / 64, 256, 0, stream>>>(emb, idx_i, zq);
    fin_kernel<<<1, 1, 0, stream>>>(loss_acc, out_loss);
}

// Round 5
// 2189.367 us; speedup vs baseline: 3.6465x; 3.6465x over previous
//
#include <hip/hip_runtime.h>

#define BB 32
#define DD 256
#define TT 1024
#define KK 8192

typedef __attribute__((ext_vector_type(2))) float f2;
typedef __attribute__((ext_vector_type(4))) float f4;

#if __has_builtin(__builtin_elementwise_fma)
#define PKFMA(a, b, c) __builtin_elementwise_fma(a, b, c)
#else
static __device__ __forceinline__ f2 pkfma_(f2 a, f2 b, f2 c) {
    f2 r; r.x = __fmaf_rn(a.x, b.x, c.x); r.y = __fmaf_rn(a.y, b.y, c.y); return r;
}
#define PKFMA(a, b, c) pkfma_(a, b, c)
#endif

// ws layout:
//   byte 0      : double loss_acc
//   byte 64     : float Bf[K]      (32768 B)   np-pairwise ||e_k||^2
//   byte 32832  : float Af[B*T]    (131072 B)  np-pairwise ||z_n||^2
//   byte 163904 : int   idx_i[B*T] (131072 B)

// Bit-exact numpy pairwise_sum of x[i]^2, n=256.
__device__ __forceinline__ float np_sq_sum256(const float* __restrict__ base, int stride) {
    float res[2];
    #pragma unroll
    for (int blk = 0; blk < 2; ++blk) {
        const int o = blk * 128;
        float r[8];
        #pragma unroll
        for (int j = 0; j < 8; ++j) {
            const float x = base[(o + j) * stride];
            r[j] = __fmul_rn(x, x);
        }
        for (int i = 8; i < 128; i += 8) {
            #pragma unroll
            for (int j = 0; j < 8; ++j) {
                const float x = base[(o + i + j) * stride];
                r[j] = __fadd_rn(r[j], __fmul_rn(x, x));
            }
        }
        res[blk] = __fadd_rn(__fadd_rn(__fadd_rn(r[0], r[1]), __fadd_rn(r[2], r[3])),
                             __fadd_rn(__fadd_rn(r[4], r[5]), __fadd_rn(r[6], r[7])));
    }
    return __fadd_rn(res[0], res[1]);
}

__global__ __launch_bounds__(256) void bsum_kernel(const float* __restrict__ emb,
                                                   float* __restrict__ Bf) {
    const int k = blockIdx.x * 256 + threadIdx.x;
    Bf[k] = np_sq_sum256(emb + (size_t)k * DD, 1);
}

__global__ __launch_bounds__(256) void asum_kernel(const float* __restrict__ z_e,
                                                   float* __restrict__ Af) {
    const int n = blockIdx.x * 256 + threadIdx.x;
    const int b = n >> 10, t = n & 1023;
    Af[n] = np_sq_sum256(z_e + ((size_t)b << 18) + t, TT);
}

// e-tile register prefetch: step st = kt*16+dc. Thread (c = lane, p = wave)
// loads codes kA = kt*512 + p*128 + c and kB = kA + 64, d-slice [dc*16, dc*16+16).
__device__ __forceinline__ void ldstage(const float* __restrict__ emb, int st,
                                        int c, int p, f4* g) {
    const int kt = st >> 4, dc = st & 15;
    const float* src = emb + (((size_t)(kt * 512 + p * 128 + c)) << 8) + dc * 16;
    #pragma unroll
    for (int m = 0; m < 4; ++m) g[m] = *(const f4*)(src + 4 * m);
    const float* src2 = src + (64 << 8);
    #pragma unroll
    for (int m = 0; m < 4; ++m) g[4 + m] = *(const f4*)(src2 + 4 * m);
}

// Scorer: 256 threads = 4 waves; wave w owns queries q = w*8 + j (j=0..7,
// wave-uniform -> z LDS reads are pure broadcasts); lane = code column.
// Thread codes per k-tile (512): k = kt0 + 64*i + lane, i=0..7, packed in
// float2 pairs (i=2p,2p+1) stored interleaved in LDS so one b128 feeds one
// pk-FMA pair for two consecutive d. Every fp32 op single-rounded, d-order
// 0..255 sequential per (q,k) -> bit-identical to numpy sgemm chain.
__global__ __launch_bounds__(256, 2) void score5_kernel(
    const float* __restrict__ z_e, const float* __restrict__ emb,
    const float* __restrict__ Bf, const float* __restrict__ Af,
    float* __restrict__ out_idx, int* __restrict__ idx_i,
    double* __restrict__ loss_acc) {
    __shared__ float zl[32 * 260];    // zl[q][d], stride 260 (pad, 16B-aligned)
    __shared__ float etp[64 * 132];   // per-col interleaved pairs, stride 132

    const int tid  = threadIdx.x;
    const int lane = tid & 63;
    const int w    = tid >> 6;
    const int n0   = blockIdx.x * 32;
    const int b    = n0 >> 10, t0 = n0 & 1023;

    // ---- stage z (once) ----
    {
        const int q = tid & 31;
        for (int d = tid >> 5; d < DD; d += 8)
            zl[q * 260 + d] = z_e[((size_t)(b * DD + d) << 10) + t0 + q];
    }
    float Aq[8];
    #pragma unroll
    for (int j = 0; j < 8; ++j) Aq[j] = Af[n0 + w * 8 + j];

    float best[8];
    int   bidx[8];
    #pragma unroll
    for (int j = 0; j < 8; ++j) { best[j] = 3.0e38f; bidx[j] = 0; }

    f4 g[8];
    ldstage(emb, 0, lane, w, g);

    for (int kt = 0; kt < 16; ++kt) {
        f2 acc[8][4];
        #pragma unroll
        for (int j = 0; j < 8; ++j)
            #pragma unroll
            for (int p2 = 0; p2 < 4; ++p2) acc[j][p2] = (f2){0.0f, 0.0f};

        for (int dc = 0; dc < 16; ++dc) {
            __syncthreads();                       // prev chunk's readers done
            {   // commit prefetched e tile, interleaving code pairs
                float* dst = etp + lane * 132 + w * 32;
                #pragma unroll
                for (int m = 0; m < 4; ++m) {
                    const f4 a = g[m], bv = g[4 + m];
                    *(f4*)(dst + 8 * m)     = __builtin_shufflevector(a, bv, 0, 4, 1, 5);
                    *(f4*)(dst + 8 * m + 4) = __builtin_shufflevector(a, bv, 2, 6, 3, 7);
                }
            }
            __syncthreads();
            const int st = kt * 16 + dc;
            ldstage(emb, st < 255 ? st + 1 : 255, lane, w, g);   // prefetch next

            #pragma unroll
            for (int s4 = 0; s4 < 4; ++s4) {
                const int dd0 = s4 * 4;
                f4 zv[8];
                #pragma unroll
                for (int j = 0; j < 8; ++j)
                    zv[j] = *(const f4*)(zl + (w * 8 + j) * 260 + dc * 16 + dd0);
                f4 ev[4][2];
                #pragma unroll
                for (int p2 = 0; p2 < 4; ++p2) {
                    const float* eb = etp + lane * 132 + p2 * 32 + dd0 * 2;
                    ev[p2][0] = *(const f4*)(eb);
                    ev[p2][1] = *(const f4*)(eb + 4);
                }
                #pragma unroll
                for (int j = 0; j < 8; ++j) {
                    #pragma unroll
                    for (int dd = 0; dd < 4; ++dd) {
                        const float zs = zv[j][dd];
                        const f2 z2 = {zs, zs};
                        #pragma unroll
                        for (int p2 = 0; p2 < 4; ++p2) {
                            const f4 evv = ev[p2][dd >> 1];
                            const f2 e2 = (dd & 1)
                                ? __builtin_shufflevector(evv, evv, 2, 3)
                                : __builtin_shufflevector(evv, evv, 0, 1);
                            acc[j][p2] = PKFMA(z2, e2, acc[j][p2]);
                        }
                    }
                }
            }
        }

        // ---- fold this k-tile (k ascending -> first-min ties kept) ----
        const int kt0 = kt * 512;
        float Bk[8];
        #pragma unroll
        for (int i = 0; i < 8; ++i) Bk[i] = Bf[kt0 + 64 * i + lane];
        #pragma unroll
        for (int p2 = 0; p2 < 4; ++p2) {
            #pragma unroll
            for (int s = 0; s < 2; ++s) {
                const int i = 2 * p2 + s;
                #pragma unroll
                for (int j = 0; j < 8; ++j) {
                    const float C    = s ? acc[j][p2].y : acc[j][p2].x;
                    const float dist = __fsub_rn(__fadd_rn(Aq[j], Bk[i]),
                                                 __fadd_rn(C, C));
                    const int k = kt0 + 64 * i + lane;
                    if (dist < best[j]) { best[j] = dist; bidx[j] = k; }
                }
            }
        }
    }

    // ---- cross-lane argmin (disjoint k per lane) ----
    #pragma unroll
    for (int j = 0; j < 8; ++j) {
        float bb = best[j];
        int   bi = bidx[j];
        #pragma unroll
        for (int off = 1; off < 64; off <<= 1) {
            const float ob = __shfl_xor(bb, off);
            const int   oi = __shfl_xor(bi, off);
            if (ob < bb || (ob == bb && oi < bi)) { bb = ob; bi = oi; }
        }
        best[j] = bb; bidx[j] = bi;
    }
    if (lane == 0) {
        double lp = 0.0;
        #pragma unroll
        for (int j = 0; j < 8; ++j) {
            const int n = n0 + w * 8 + j;
            out_idx[n] = (float)bidx[j];
            idx_i[n]   = bidx[j];
            lp += (double)best[j];
        }
        atomicAdd(loss_acc, lp);
    }
}

__global__ __launch_bounds__(256) void gather_kernel(const float* __restrict__ emb,
                                                     const int* __restrict__ idx_i,
                                                     float* __restrict__ zq) {
    const int blk = blockIdx.x;
    const int b  = blk >> 4;
    const int t0 = (blk & 15) * 64;
    const int q  = threadIdx.x & 63;
    const int dc = threadIdx.x >> 6;
    const int n  = b * TT + t0 + q;
    const int k  = idx_i[n];
    const float4* erow = reinterpret_cast<const float4*>(emb + (size_t)k * DD + dc * 64);
    #pragma unroll
    for (int jj = 0; jj < 16; ++jj) {
        const float4 v = erow[jj];
        const int d = dc * 64 + jj * 4;
        zq[(size_t)(b * DD + d + 0) * TT + t0 + q] = v.x;
        zq[(size_t)(b * DD + d + 1) * TT + t0 + q] = v.y;
        zq[(size_t)(b * DD + d + 2) * TT + t0 + q] = v.z;
        zq[(size_t)(b * DD + d + 3) * TT + t0 + q] = v.w;
    }
}

__global__ void fin_kernel(const double* __restrict__ loss_acc,
                           float* __restrict__ out_loss) {
    out_loss[0] = (float)(loss_acc[0] * (1.0 / ((double)BB * DD * TT)));
}

extern "C" void kernel_launch(void* const* d_in, const int* in_sizes, int n_in,
                              void* d_out, int out_size, void* d_ws, size_t ws_size,
                              hipStream_t stream) {
    const float* z_e = (const float*)d_in[0];
    const float* emb = (const float*)d_in[1];

    float* out      = (float*)d_out;
    float* zq       = out;
    float* out_loss = out + (size_t)BB * DD * TT;
    float* out_idx  = out_loss + 1;

    double* loss_acc = (double*)d_ws;
    float*  Bf       = (float*)((char*)d_ws + 64);
    float*  Af       = (float*)((char*)d_ws + 64 + (size_t)KK * 4);
    int*    idx_i    = (int*)((char*)d_ws + 64 + (size_t)KK * 4 + (size_t)BB * TT * 4);

    hipMemsetAsync(d_ws, 0, 64, stream);
    bsum_kernel<<<KK / 256, 256, 0, stream>>>(emb, Bf);
    asum_kernel<<<(BB * TT) / 256, 256, 0, stream>>>(z_e, Af);
    score5_kernel<<<(BB * TT) / 32, 256, 0, stream>>>(z_e, emb, Bf, Af, out_idx, idx_i, loss_acc);
    gather_kernel<<<(BB * TT) / 64, 256, 0, stream>>>(emb, idx_i, zq);
    fin_kernel<<<1, 1, 0, stream>>>(loss_acc, out_loss);
}

// Round 6
// 1812.081 us; speedup vs baseline: 4.4057x; 1.2082x over previous
//
#include <hip/hip_runtime.h>
#include <stdint.h>

#define BB 32
#define DD 256
#define TT 1024
#define KK 8192

typedef __attribute__((ext_vector_type(2))) float f2;
typedef __attribute__((ext_vector_type(4))) float f4;
typedef __attribute__((ext_vector_type(8))) short bfrag;   // 8 bf16 = 4 VGPR
typedef __attribute__((ext_vector_type(4))) float f4acc;   // MFMA acc

#if __has_builtin(__builtin_elementwise_fma)
#define PKFMA(a, b, c) __builtin_elementwise_fma(a, b, c)
#else
static __device__ __forceinline__ f2 pkfma_(f2 a, f2 b, f2 c) {
    f2 r; r.x = __fmaf_rn(a.x, b.x, c.x); r.y = __fmaf_rn(a.y, b.y, c.y); return r;
}
#define PKFMA(a, b, c) pkfma_(a, b, c)
#endif

#define GLD16(gp, lp)                                                          \
    __builtin_amdgcn_global_load_lds(                                          \
        (const __attribute__((address_space(1))) uint32_t*)(gp),               \
        (__attribute__((address_space(3))) uint32_t*)(lp), 16, 0, 0)

#define MU 1.5e-4f

// ---------------- fast-path ws layout (bytes) ----------------
#define WS_LOSS   0          // double
#define WS_CNT    8          // int
#define WS_BF     64         // float[8192]
#define WS_AF     32832      // float[32768]
#define WS_IDX    163904     // int[32768]
#define WS_THR    294976     // float[32768]
#define WS_WIN    426048     // u64[32768]
#define WS_TMIN   688192     // float[32768*64]
#define WS_LIST   9076800    // int[32768*64]
#define WS_ZH     17465408   // ushort[32768*256]
#define WS_ZL     34242624
#define WS_EH     51019840   // ushort[8192*256]
#define WS_EL     55214144
#define WS_NEED   59408448

__device__ __forceinline__ unsigned short bf16_rne(float x) {
    uint32_t u = __float_as_uint(x);
    uint32_t r = (u + 0x7FFFu + ((u >> 16) & 1u)) >> 16;
    return (unsigned short)r;
}
__device__ __forceinline__ float bf16_to_f(unsigned short h) {
    return __uint_as_float(((uint32_t)h) << 16);
}

// Bit-exact numpy pairwise_sum of x[i]^2, n=256.
__device__ __forceinline__ float np_sq_sum256(const float* __restrict__ base, int stride) {
    float res[2];
    #pragma unroll
    for (int blk = 0; blk < 2; ++blk) {
        const int o = blk * 128;
        float r[8];
        #pragma unroll
        for (int j = 0; j < 8; ++j) {
            const float x = base[(o + j) * stride];
            r[j] = __fmul_rn(x, x);
        }
        for (int i = 8; i < 128; i += 8) {
            #pragma unroll
            for (int j = 0; j < 8; ++j) {
                const float x = base[(o + i + j) * stride];
                r[j] = __fadd_rn(r[j], __fmul_rn(x, x));
            }
        }
        res[blk] = __fadd_rn(__fadd_rn(__fadd_rn(r[0], r[1]), __fadd_rn(r[2], r[3])),
                             __fadd_rn(__fadd_rn(r[4], r[5]), __fadd_rn(r[6], r[7])));
    }
    return __fadd_rn(res[0], res[1]);
}

__global__ __launch_bounds__(256) void bsum_kernel(const float* __restrict__ emb,
                                                   float* __restrict__ Bf) {
    const int k = blockIdx.x * 256 + threadIdx.x;
    Bf[k] = np_sq_sum256(emb + (size_t)k * DD, 1);
}

__global__ __launch_bounds__(256) void asum_kernel(const float* __restrict__ z_e,
                                                   float* __restrict__ Af) {
    const int n = blockIdx.x * 256 + threadIdx.x;
    const int b = n >> 10, t = n & 1023;
    Af[n] = np_sq_sum256(z_e + ((size_t)b << 18) + t, TT);
}

// ---- split z into bf16 hi/lo, transposed to [q][d] ----
__global__ __launch_bounds__(256) void splitz_kernel(const float* __restrict__ z_e,
                                                     unsigned short* __restrict__ zh,
                                                     unsigned short* __restrict__ zl) {
    __shared__ unsigned short uh[64][260], ul[64][260];
    const int tid = threadIdx.x, l = tid & 63, wy = tid >> 6;
    const int n0 = blockIdx.x * 64;         // 512 blocks
    const int b = n0 >> 10, t0 = n0 & 1023;
    for (int d = wy; d < DD; d += 4) {
        const float x = z_e[(size_t)(b * DD + d) * TT + t0 + l];
        const unsigned short h = bf16_rne(x);
        uh[l][d] = h;
        ul[l][d] = bf16_rne(__fsub_rn(x, bf16_to_f(h)));
    }
    __syncthreads();
    const int r = tid >> 2, seg = (tid & 3) * 64;   // 64 ushorts = 128 B per copy
    const uint2* sh = (const uint2*)&uh[r][seg];
    const uint2* sl = (const uint2*)&ul[r][seg];
    uint2* dh = (uint2*)(zh + (size_t)(n0 + r) * DD + seg);
    uint2* dl = (uint2*)(zl + (size_t)(n0 + r) * DD + seg);
    #pragma unroll
    for (int i = 0; i < 16; ++i) { dh[i] = sh[i]; dl[i] = sl[i]; }
}

// ---- split e into bf16 hi/lo (layout already [k][d]) ----
__global__ __launch_bounds__(256) void splite_kernel(const float* __restrict__ emb,
                                                     unsigned short* __restrict__ eh,
                                                     unsigned short* __restrict__ el) {
    const int i0 = (blockIdx.x * 256 + threadIdx.x) * 4;   // 2048 blocks
    const f4 v = *(const f4*)(emb + i0);
    ushort4 h, l;
    h.x = bf16_rne(v.x); l.x = bf16_rne(__fsub_rn(v.x, bf16_to_f(h.x)));
    h.y = bf16_rne(v.y); l.y = bf16_rne(__fsub_rn(v.y, bf16_to_f(h.y)));
    h.z = bf16_rne(v.z); l.z = bf16_rne(__fsub_rn(v.z, bf16_to_f(h.z)));
    h.w = bf16_rne(v.w); l.w = bf16_rne(__fsub_rn(v.w, bf16_to_f(h.w)));
    *(ushort4*)(eh + i0) = h;
    *(ushort4*)(el + i0) = l;
}

// ---- K1: split-bf16 MFMA scorer. Block = 128q x 128k tile, 4 waves (2x2 of
// 64x64). Per K-chunk (BK=32): stage Ah/Al/Bh/Bl via global_load_lds(16B),
// 48 MFMA (hh + hl + lh). Epilogue: per-query min of approx dist over the
// 128 codes -> tmp_min[q][kb]. ----
__global__ __launch_bounds__(256) void mfma_score_kernel(
    const unsigned short* __restrict__ zh, const unsigned short* __restrict__ zl,
    const unsigned short* __restrict__ eh, const unsigned short* __restrict__ el,
    const float* __restrict__ Af, const float* __restrict__ Bf,
    float* __restrict__ tmp_min) {
    __shared__ unsigned short Ah[4096], Al[4096], Bh[4096], Bl[4096];  // [128][32]
    __shared__ float sval[256];    // [128 q][2 khalf]

    const int tid  = threadIdx.x;
    const int lane = tid & 63;
    const int w    = tid >> 6;
    const int quad = lane >> 4;
    const int l15  = lane & 15;
    const int qt   = blockIdx.x >> 6;
    const int kb   = blockIdx.x & 63;
    const int qh   = (w & 1) * 64;
    const int kh   = (w >> 1) * 64;

    // staging descriptors: instr n = w*2+s covers rows 16n..16n+15
    const int n0 = w * 2, n1 = n0 + 1;
    const int r0 = 16 * n0 + (lane >> 2), r1 = 16 * n1 + (lane >> 2);
    const int cs = (lane & 3) * 8;                       // ushort offset in row
    const unsigned short* gA0h = zh + (size_t)(qt * 128 + r0) * DD + cs;
    const unsigned short* gA1h = zh + (size_t)(qt * 128 + r1) * DD + cs;
    const unsigned short* gA0l = zl + (size_t)(qt * 128 + r0) * DD + cs;
    const unsigned short* gA1l = zl + (size_t)(qt * 128 + r1) * DD + cs;
    const unsigned short* gB0h = eh + (size_t)(kb * 128 + r0) * DD + cs;
    const unsigned short* gB1h = eh + (size_t)(kb * 128 + r1) * DD + cs;
    const unsigned short* gB0l = el + (size_t)(kb * 128 + r0) * DD + cs;
    const unsigned short* gB1l = el + (size_t)(kb * 128 + r1) * DD + cs;

    f4acc acc[4][4];
    #pragma unroll
    for (int i = 0; i < 4; ++i)
        #pragma unroll
        for (int j = 0; j < 4; ++j) acc[i][j] = (f4acc){0.f, 0.f, 0.f, 0.f};

    for (int ch = 0; ch < 8; ++ch) {
        const int kk = ch * 32;
        GLD16(gA0h + kk, Ah + n0 * 512);
        GLD16(gA1h + kk, Ah + n1 * 512);
        GLD16(gA0l + kk, Al + n0 * 512);
        GLD16(gA1l + kk, Al + n1 * 512);
        GLD16(gB0h + kk, Bh + n0 * 512);
        GLD16(gB1h + kk, Bh + n1 * 512);
        GLD16(gB0l + kk, Bl + n0 * 512);
        GLD16(gB1l + kk, Bl + n1 * 512);
        __syncthreads();

        bfrag ah[4], al[4];
        #pragma unroll
        for (int i = 0; i < 4; ++i) {
            const int off = (qh + i * 16 + l15) * 32 + quad * 8;
            ah[i] = *(const bfrag*)(Ah + off);
            al[i] = *(const bfrag*)(Al + off);
        }
        #pragma unroll
        for (int j = 0; j < 4; ++j) {
            const int off = (kh + j * 16 + l15) * 32 + quad * 8;
            const bfrag bh = *(const bfrag*)(Bh + off);
            const bfrag bl = *(const bfrag*)(Bl + off);
            #pragma unroll
            for (int i = 0; i < 4; ++i) {
                acc[i][j] = __builtin_amdgcn_mfma_f32_16x16x32_bf16(ah[i], bh, acc[i][j], 0, 0, 0);
                acc[i][j] = __builtin_amdgcn_mfma_f32_16x16x32_bf16(ah[i], bl, acc[i][j], 0, 0, 0);
                acc[i][j] = __builtin_amdgcn_mfma_f32_16x16x32_bf16(al[i], bh, acc[i][j], 0, 0, 0);
            }
        }
        __syncthreads();
    }

    // epilogue: approx dist + per-q min over this block's 128 codes
    float bfv[4];
    #pragma unroll
    for (int j = 0; j < 4; ++j) bfv[j] = Bf[kb * 128 + kh + j * 16 + l15];
    #pragma unroll
    for (int i = 0; i < 4; ++i) {
        #pragma unroll
        for (int reg = 0; reg < 4; ++reg) {
            const float af = Af[qt * 128 + qh + i * 16 + quad * 4 + reg];
            float v = 3.0e38f;
            #pragma unroll
            for (int j = 0; j < 4; ++j) {
                const float c = acc[i][j][reg];
                const float d = (af + bfv[j]) - (c + c);
                v = fminf(v, d);
            }
            #pragma unroll
            for (int off = 1; off < 16; off <<= 1) v = fminf(v, __shfl_xor(v, off));
            if (l15 == 0) sval[(qh + i * 16 + quad * 4 + reg) * 2 + (w >> 1)] = v;
        }
    }
    __syncthreads();
    if (tid < 128) {
        const float v = fminf(sval[tid * 2], sval[tid * 2 + 1]);
        tmp_min[(size_t)(qt * 128 + tid) * 64 + kb] = v;
    }
}

// ---- K2: thr[q] = min_kb + MU; init winner ----
__global__ __launch_bounds__(256) void thr_kernel(const float* __restrict__ tmp_min,
                                                  float* __restrict__ thr,
                                                  unsigned long long* __restrict__ winner) {
    const int q = blockIdx.x * 256 + threadIdx.x;
    const f4* p = (const f4*)(tmp_min + (size_t)q * 64);
    float m = 3.0e38f;
    #pragma unroll
    for (int i = 0; i < 16; ++i) {
        const f4 v = p[i];
        m = fminf(m, fminf(fminf(v.x, v.y), fminf(v.z, v.w)));
    }
    thr[q] = m + MU;
    winner[q] = ~0ULL;
}

// ---- K3a: compact qualifying (q, kb) pairs ----
__global__ __launch_bounds__(256) void compact_kernel(const float* __restrict__ tmp_min,
                                                      const float* __restrict__ thr,
                                                      int* __restrict__ list,
                                                      int* __restrict__ cnt) {
    const int id = blockIdx.x * 256 + threadIdx.x;   // 2M pairs
    if (tmp_min[id] <= thr[id >> 6]) {
        const int pos = atomicAdd(cnt, 1);
        list[pos] = id;
    }
}

// ---- K3b: exact re-rank of qualifying blocks (bit-exact r5 formula) ----
__global__ __launch_bounds__(256) void rescan_kernel(
    const float* __restrict__ z_e, const float* __restrict__ emb,
    const float* __restrict__ Af, const float* __restrict__ Bf,
    const int* __restrict__ list, const int* __restrict__ cnt,
    unsigned long long* __restrict__ winner) {
    __shared__ float zbuf[4][256];
    const int tid = threadIdx.x, lane = tid & 63, w = tid >> 6;
    const int nw = gridDim.x * 4;
    const int wid = blockIdx.x * 4 + w;
    const int n = *cnt;
    for (int it = wid; it < n; it += nw) {
        const int id = list[it];
        const int q = id >> 6, kb = id & 63;
        const int b = q >> 10, t = q & 1023;
        {   // stage z row (wave-local)
            const float* zp = z_e + ((size_t)b << 18) + t;
            f4 v;
            v.x = zp[(size_t)(lane * 4 + 0) << 10];
            v.y = zp[(size_t)(lane * 4 + 1) << 10];
            v.z = zp[(size_t)(lane * 4 + 2) << 10];
            v.w = zp[(size_t)(lane * 4 + 3) << 10];
            *(f4*)&zbuf[w][lane * 4] = v;
        }
        const int k0 = kb * 128 + lane, k1 = k0 + 64;
        const float* e0 = emb + (size_t)k0 * DD;
        const float* e1 = emb + (size_t)k1 * DD;
        float c0 = 0.0f, c1 = 0.0f;
        #pragma unroll 8
        for (int d = 0; d < DD; ++d) {
            const float zv = zbuf[w][d];
            c0 = __fmaf_rn(zv, e0[d], c0);
            c1 = __fmaf_rn(zv, e1[d], c1);
        }
        const float afq = Af[q];
        const float d0 = __fsub_rn(__fadd_rn(afq, Bf[k0]), __fadd_rn(c0, c0));
        const float d1 = __fsub_rn(__fadd_rn(afq, Bf[k1]), __fadd_rn(c1, c1));
        float bv; int bk;
        if (d0 <= d1) { bv = d0; bk = k0; } else { bv = d1; bk = k1; }
        #pragma unroll
        for (int off = 1; off < 64; off <<= 1) {
            const float ob = __shfl_xor(bv, off);
            const int   ok = __shfl_xor(bk, off);
            if (ob < bv || (ob == bv && ok < bk)) { bv = ob; bk = ok; }
        }
        if (lane == 0)
            atomicMin(winner + q,
                      (((unsigned long long)__float_as_uint(bv)) << 32) | (unsigned)bk);
    }
}

// ---- K4: finalize idx + loss ----
__global__ __launch_bounds__(256) void final_kernel(
    const unsigned long long* __restrict__ winner, float* __restrict__ out_idx,
    int* __restrict__ idx_i, double* __restrict__ loss_acc) {
    __shared__ double ls[4];
    const int tid = threadIdx.x, lane = tid & 63, w = tid >> 6;
    const int q = blockIdx.x * 256 + tid;
    const unsigned long long wv = winner[q];
    const int k = (int)(wv & 0xFFFFFFFFu);
    idx_i[q] = k;
    out_idx[q] = (float)k;
    double s = (double)__uint_as_float((unsigned)(wv >> 32));
    #pragma unroll
    for (int off = 1; off < 64; off <<= 1) s += __shfl_xor(s, off);
    if (lane == 0) ls[w] = s;
    __syncthreads();
    if (tid == 0) atomicAdd(loss_acc, ls[0] + ls[1] + ls[2] + ls[3]);
}

// ================== r5 fallback scorer (ws too small) ==================
__device__ __forceinline__ void ldstage(const float* __restrict__ emb, int st,
                                        int c, int p, f4* g) {
    const int kt = st >> 4, dc = st & 15;
    const float* src = emb + (((size_t)(kt * 512 + p * 128 + c)) << 8) + dc * 16;
    #pragma unroll
    for (int m = 0; m < 4; ++m) g[m] = *(const f4*)(src + 4 * m);
    const float* src2 = src + (64 << 8);
    #pragma unroll
    for (int m = 0; m < 4; ++m) g[4 + m] = *(const f4*)(src2 + 4 * m);
}

__global__ __launch_bounds__(256, 2) void score5_kernel(
    const float* __restrict__ z_e, const float* __restrict__ emb,
    const float* __restrict__ Bf, const float* __restrict__ Af,
    float* __restrict__ out_idx, int* __restrict__ idx_i,
    double* __restrict__ loss_acc) {
    __shared__ float zl[32 * 260];
    __shared__ float etp[64 * 132];
    const int tid = threadIdx.x;
    const int lane = tid & 63;
    const int w = tid >> 6;
    const int n0 = blockIdx.x * 32;
    const int b = n0 >> 10, t0 = n0 & 1023;
    {
        const int q = tid & 31;
        for (int d = tid >> 5; d < DD; d += 8)
            zl[q * 260 + d] = z_e[((size_t)(b * DD + d) << 10) + t0 + q];
    }
    float Aq[8];
    #pragma unroll
    for (int j = 0; j < 8; ++j) Aq[j] = Af[n0 + w * 8 + j];
    float best[8];
    int bidx[8];
    #pragma unroll
    for (int j = 0; j < 8; ++j) { best[j] = 3.0e38f; bidx[j] = 0; }
    f4 g[8];
    ldstage(emb, 0, lane, w, g);
    for (int kt = 0; kt < 16; ++kt) {
        f2 acc[8][4];
        #pragma unroll
        for (int j = 0; j < 8; ++j)
            #pragma unroll
            for (int p2 = 0; p2 < 4; ++p2) acc[j][p2] = (f2){0.0f, 0.0f};
        for (int dc = 0; dc < 16; ++dc) {
            __syncthreads();
            {
                float* dst = etp + lane * 132 + w * 32;
                #pragma unroll
                for (int m = 0; m < 4; ++m) {
                    const f4 a = g[m], bv = g[4 + m];
                    *(f4*)(dst + 8 * m)     = __builtin_shufflevector(a, bv, 0, 4, 1, 5);
                    *(f4*)(dst + 8 * m + 4) = __builtin_shufflevector(a, bv, 2, 6, 3, 7);
                }
            }
            __syncthreads();
            const int st = kt * 16 + dc;
            ldstage(emb, st < 255 ? st + 1 : 255, lane, w, g);
            #pragma unroll
            for (int s4 = 0; s4 < 4; ++s4) {
                const int dd0 = s4 * 4;
                f4 zv[8];
                #pragma unroll
                for (int j = 0; j < 8; ++j)
                    zv[j] = *(const f4*)(zl + (w * 8 + j) * 260 + dc * 16 + dd0);
                f4 ev[4][2];
                #pragma unroll
                for (int p2 = 0; p2 < 4; ++p2) {
                    const float* eb = etp + lane * 132 + p2 * 32 + dd0 * 2;
                    ev[p2][0] = *(const f4*)(eb);
                    ev[p2][1] = *(const f4*)(eb + 4);
                }
                #pragma unroll
                for (int j = 0; j < 8; ++j) {
                    #pragma unroll
                    for (int dd = 0; dd < 4; ++dd) {
                        const float zs = zv[j][dd];
                        const f2 z2 = {zs, zs};
                        #pragma unroll
                        for (int p2 = 0; p2 < 4; ++p2) {
                            const f4 evv = ev[p2][dd >> 1];
                            const f2 e2 = (dd & 1)
                                ? __builtin_shufflevector(evv, evv, 2, 3)
                                : __builtin_shufflevector(evv, evv, 0, 1);
                            acc[j][p2] = PKFMA(z2, e2, acc[j][p2]);
                        }
                    }
                }
            }
        }
        const int kt0 = kt * 512;
        float Bk[8];
        #pragma unroll
        for (int i = 0; i < 8; ++i) Bk[i] = Bf[kt0 + 64 * i + lane];
        #pragma unroll
        for (int p2 = 0; p2 < 4; ++p2) {
            #pragma unroll
            for (int s = 0; s < 2; ++s) {
                const int i = 2 * p2 + s;
                #pragma unroll
                for (int j = 0; j < 8; ++j) {
                    const float C = s ? acc[j][p2].y : acc[j][p2].x;
                    const float dist = __fsub_rn(__fadd_rn(Aq[j], Bk[i]), __fadd_rn(C, C));
                    const int k = kt0 + 64 * i + lane;
                    if (dist < best[j]) { best[j] = dist; bidx[j] = k; }
                }
            }
        }
    }
    #pragma unroll
    for (int j = 0; j < 8; ++j) {
        float bb = best[j];
        int bi = bidx[j];
        #pragma unroll
        for (int off = 1; off < 64; off <<= 1) {
            const float ob = __shfl_xor(bb, off);
            const int oi = __shfl_xor(bi, off);
            if (ob < bb || (ob == bb && oi < bi)) { bb = ob; bi = oi; }
        }
        best[j] = bb; bidx[j] = bi;
    }
    if (lane == 0) {
        double lp = 0.0;
        #pragma unroll
        for (int j = 0; j < 8; ++j) {
            const int n = n0 + w * 8 + j;
            out_idx[n] = (float)bidx[j];
            idx_i[n] = bidx[j];
            lp += (double)best[j];
        }
        atomicAdd(loss_acc, lp);
    }
}

// ================== shared epilogue kernels ==================
__global__ __launch_bounds__(256) void gather_kernel(const float* __restrict__ emb,
                                                     const int* __restrict__ idx_i,
                                                     float* __restrict__ zq) {
    const int blk = blockIdx.x;
    const int b = blk >> 4;
    const int t0 = (blk & 15) * 64;
    const int q = threadIdx.x & 63;
    const int dc = threadIdx.x >> 6;
    const int n = b * TT + t0 + q;
    const int k = idx_i[n];
    const f4* erow = (const f4*)(emb + (size_t)k * DD + dc * 64);
    #pragma unroll
    for (int jj = 0; jj < 16; ++jj) {
        const f4 v = erow[jj];
        const int d = dc * 64 + jj * 4;
        zq[(size_t)(b * DD + d + 0) * TT + t0 + q] = v.x;
        zq[(size_t)(b * DD + d + 1) * TT + t0 + q] = v.y;
        zq[(size_t)(b * DD + d + 2) * TT + t0 + q] = v.z;
        zq[(size_t)(b * DD + d + 3) * TT + t0 + q] = v.w;
    }
}

__global__ void fin_kernel(const double* __restrict__ loss_acc,
                           float* __restrict__ out_loss) {
    out_loss[0] = (float)(loss_acc[0] * (1.0 / ((double)BB * DD * TT)));
}

extern "C" void kernel_launch(void* const* d_in, const int* in_sizes, int n_in,
                              void* d_out, int out_size, void* d_ws, size_t ws_size,
                              hipStream_t stream) {
    const float* z_e = (const float*)d_in[0];
    const float* emb = (const float*)d_in[1];

    float* out      = (float*)d_out;
    float* zq       = out;
    float* out_loss = out + (size_t)BB * DD * TT;
    float* out_idx  = out_loss + 1;

    char* ws = (char*)d_ws;
    double* loss_acc = (double*)(ws + WS_LOSS);
    float*  Bf       = (float*)(ws + WS_BF);
    float*  Af       = (float*)(ws + WS_AF);
    int*    idx_i    = (int*)(ws + WS_IDX);

    hipMemsetAsync(d_ws, 0, 64, stream);
    bsum_kernel<<<KK / 256, 256, 0, stream>>>(emb, Bf);
    asum_kernel<<<(BB * TT) / 256, 256, 0, stream>>>(z_e, Af);

    if (ws_size >= (size_t)WS_NEED) {
        int*    cnt     = (int*)(ws + WS_CNT);
        float*  thr     = (float*)(ws + WS_THR);
        unsigned long long* winner = (unsigned long long*)(ws + WS_WIN);
        float*  tmp_min = (float*)(ws + WS_TMIN);
        int*    list    = (int*)(ws + WS_LIST);
        unsigned short* zh = (unsigned short*)(ws + WS_ZH);
        unsigned short* zl = (unsigned short*)(ws + WS_ZL);
        unsigned short* eh = (unsigned short*)(ws + WS_EH);
        unsigned short* el = (unsigned short*)(ws + WS_EL);

        splitz_kernel<<<(BB * TT) / 64, 256, 0, stream>>>(z_e, zh, zl);
        splite_kernel<<<(KK * DD) / 1024, 256, 0, stream>>>(emb, eh, el);
        mfma_score_kernel<<<(BB * TT / 128) * 64, 256, 0, stream>>>(zh, zl, eh, el, Af, Bf, tmp_min);
        thr_kernel<<<(BB * TT) / 256, 256, 0, stream>>>(tmp_min, thr, winner);
        compact_kernel<<<(BB * TT * 64) / 256, 256, 0, stream>>>(tmp_min, thr, list, cnt);
        rescan_kernel<<<512, 256, 0, stream>>>(z_e, emb, Af, Bf, list, cnt, winner);
        final_kernel<<<(BB * TT) / 256, 256, 0, stream>>>(winner, out_idx, idx_i, loss_acc);
    } else {
        score5_kernel<<<(BB * TT) / 32, 256, 0, stream>>>(z_e, emb, Bf, Af, out_idx, idx_i, loss_acc);
    }

    gather_kernel<<<(BB * TT) / 64, 256, 0, stream>>>(emb, idx_i, zq);
    fin_kernel<<<1, 1, 0, stream>>>(loss_acc, out_loss);
}

// Round 7
// 1339.688 us; speedup vs baseline: 5.9593x; 1.3526x over previous
//
#include <hip/hip_runtime.h>
#include <stdint.h>

#define BB 32
#define DD 256
#define TT 1024
#define KK 8192

typedef __attribute__((ext_vector_type(2))) float f2;
typedef __attribute__((ext_vector_type(4))) float f4;
typedef __attribute__((ext_vector_type(8))) short bfrag;   // 8 bf16 = 4 VGPR
typedef __attribute__((ext_vector_type(4))) float f4acc;   // MFMA acc

#if __has_builtin(__builtin_elementwise_fma)
#define PKFMA(a, b, c) __builtin_elementwise_fma(a, b, c)
#else
static __device__ __forceinline__ f2 pkfma_(f2 a, f2 b, f2 c) {
    f2 r; r.x = __fmaf_rn(a.x, b.x, c.x); r.y = __fmaf_rn(a.y, b.y, c.y); return r;
}
#define PKFMA(a, b, c) pkfma_(a, b, c)
#endif

#define GLD16(gp, lp)                                                          \
    __builtin_amdgcn_global_load_lds(                                          \
        (const __attribute__((address_space(1))) uint32_t*)(gp),               \
        (__attribute__((address_space(3))) uint32_t*)(lp), 16, 0, 0)

#define MU 1.0e-4f
#define LIST_CAP 2097152

// ---------------- fast-path ws layout (bytes) ----------------
#define WS_LOSS   0
#define WS_CNT    8
#define WS_BF     64
#define WS_AF     32832
#define WS_IDX    163904
#define WS_THR    294976
#define WS_WIN    426048
#define WS_ZT     688192
#define WS_TMIN   34242624
#define WS_LIST   67797056
#define WS_ZH     76185664
#define WS_ZL     92962880
#define WS_EH     109740096
#define WS_EL     113934400
#define WS_NEED   118128704

__device__ __forceinline__ unsigned short bf16_rne(float x) {
    uint32_t u = __float_as_uint(x);
    uint32_t r = (u + 0x7FFFu + ((u >> 16) & 1u)) >> 16;
    return (unsigned short)r;
}
__device__ __forceinline__ float bf16_to_f(unsigned short h) {
    return __uint_as_float(((uint32_t)h) << 16);
}

// Bit-exact numpy pairwise_sum of x[i]^2, n=256.
__device__ __forceinline__ float np_sq_sum256(const float* __restrict__ base, int stride) {
    float res[2];
    #pragma unroll
    for (int blk = 0; blk < 2; ++blk) {
        const int o = blk * 128;
        float r[8];
        #pragma unroll
        for (int j = 0; j < 8; ++j) {
            const float x = base[(o + j) * stride];
            r[j] = __fmul_rn(x, x);
        }
        for (int i = 8; i < 128; i += 8) {
            #pragma unroll
            for (int j = 0; j < 8; ++j) {
                const float x = base[(o + i + j) * stride];
                r[j] = __fadd_rn(r[j], __fmul_rn(x, x));
            }
        }
        res[blk] = __fadd_rn(__fadd_rn(__fadd_rn(r[0], r[1]), __fadd_rn(r[2], r[3])),
                             __fadd_rn(__fadd_rn(r[4], r[5]), __fadd_rn(r[6], r[7])));
    }
    return __fadd_rn(res[0], res[1]);
}

__global__ __launch_bounds__(256) void bsum_kernel(const float* __restrict__ emb,
                                                   float* __restrict__ Bf) {
    const int k = blockIdx.x * 256 + threadIdx.x;
    Bf[k] = np_sq_sum256(emb + (size_t)k * DD, 1);
}

__global__ __launch_bounds__(256) void asum_kernel(const float* __restrict__ z_e,
                                                   float* __restrict__ Af) {
    const int n = blockIdx.x * 256 + threadIdx.x;
    const int b = n >> 10, t = n & 1023;
    Af[n] = np_sq_sum256(z_e + ((size_t)b << 18) + t, TT);
}

// ---- transpose z: [B,D,T] -> zt[q][d] fp32 (64q x 64d tiles via LDS) ----
__global__ __launch_bounds__(256) void ztrans_kernel(const float* __restrict__ z_e,
                                                     float* __restrict__ zt) {
    __shared__ float tile[64][65];
    const int tid = threadIdx.x;
    const int n0 = (blockIdx.x >> 2) * 64;
    const int d0 = (blockIdx.x & 3) * 64;
    const int b = n0 >> 10, t0 = n0 & 1023;
    const int tc = tid & 63, dr0 = tid >> 6;
    #pragma unroll
    for (int i = 0; i < 16; ++i) {
        const int d = dr0 + i * 4;
        tile[d][tc] = z_e[(size_t)(b * DD + d0 + d) * TT + t0 + tc];
    }
    __syncthreads();
    const int q = tid >> 2, c0 = (tid & 3) * 16;
    float* dst = zt + (size_t)(n0 + q) * DD + d0 + c0;
    #pragma unroll
    for (int i = 0; i < 4; ++i) {
        f4 v;
        v.x = tile[c0 + 4 * i + 0][q];
        v.y = tile[c0 + 4 * i + 1][q];
        v.z = tile[c0 + 4 * i + 2][q];
        v.w = tile[c0 + 4 * i + 3][q];
        *(f4*)(dst + 4 * i) = v;
    }
}

// ---- split z into bf16 hi/lo, transposed to [q][d] ----
__global__ __launch_bounds__(256) void splitz_kernel(const float* __restrict__ z_e,
                                                     unsigned short* __restrict__ zh,
                                                     unsigned short* __restrict__ zl) {
    __shared__ unsigned short uh[64][260], ul[64][260];
    const int tid = threadIdx.x, l = tid & 63, wy = tid >> 6;
    const int n0 = blockIdx.x * 64;
    const int b = n0 >> 10, t0 = n0 & 1023;
    for (int d = wy; d < DD; d += 4) {
        const float x = z_e[(size_t)(b * DD + d) * TT + t0 + l];
        const unsigned short h = bf16_rne(x);
        uh[l][d] = h;
        ul[l][d] = bf16_rne(__fsub_rn(x, bf16_to_f(h)));
    }
    __syncthreads();
    const int r = tid >> 2, seg = (tid & 3) * 64;
    const uint2* sh = (const uint2*)&uh[r][seg];
    const uint2* sl = (const uint2*)&ul[r][seg];
    uint2* dh = (uint2*)(zh + (size_t)(n0 + r) * DD + seg);
    uint2* dl = (uint2*)(zl + (size_t)(n0 + r) * DD + seg);
    #pragma unroll
    for (int i = 0; i < 16; ++i) { dh[i] = sh[i]; dl[i] = sl[i]; }
}

// ---- split e into bf16 hi/lo ----
__global__ __launch_bounds__(256) void splite_kernel(const float* __restrict__ emb,
                                                     unsigned short* __restrict__ eh,
                                                     unsigned short* __restrict__ el) {
    const int i0 = (blockIdx.x * 256 + threadIdx.x) * 4;
    const f4 v = *(const f4*)(emb + i0);
    ushort4 h, l;
    h.x = bf16_rne(v.x); l.x = bf16_rne(__fsub_rn(v.x, bf16_to_f(h.x)));
    h.y = bf16_rne(v.y); l.y = bf16_rne(__fsub_rn(v.y, bf16_to_f(h.y)));
    h.z = bf16_rne(v.z); l.z = bf16_rne(__fsub_rn(v.z, bf16_to_f(h.z)));
    h.w = bf16_rne(v.w); l.w = bf16_rne(__fsub_rn(v.w, bf16_to_f(h.w)));
    *(ushort4*)(eh + i0) = h;
    *(ushort4*)(el + i0) = l;
}

// ---- K1: split-bf16 MFMA scorer; per-(q, 32-code-group) min out ----
__global__ __launch_bounds__(256) void mfma_score_kernel(
    const unsigned short* __restrict__ zh, const unsigned short* __restrict__ zl,
    const unsigned short* __restrict__ eh, const unsigned short* __restrict__ el,
    const float* __restrict__ Af, const float* __restrict__ Bf,
    float* __restrict__ tmp_min) {
    __shared__ unsigned short Ah[4096], Al[4096], Bh[4096], Bl[4096];  // [128][32]

    const int tid  = threadIdx.x;
    const int lane = tid & 63;
    const int w    = tid >> 6;
    const int quad = lane >> 4;
    const int l15  = lane & 15;
    const int qt   = blockIdx.x >> 6;
    const int kb   = blockIdx.x & 63;
    const int qh   = (w & 1) * 64;
    const int kh   = (w >> 1) * 64;

    const int n0 = w * 2, n1 = n0 + 1;
    const int r0 = 16 * n0 + (lane >> 2), r1 = 16 * n1 + (lane >> 2);
    const int cs = (lane & 3) * 8;
    const unsigned short* gA0h = zh + (size_t)(qt * 128 + r0) * DD + cs;
    const unsigned short* gA1h = zh + (size_t)(qt * 128 + r1) * DD + cs;
    const unsigned short* gA0l = zl + (size_t)(qt * 128 + r0) * DD + cs;
    const unsigned short* gA1l = zl + (size_t)(qt * 128 + r1) * DD + cs;
    const unsigned short* gB0h = eh + (size_t)(kb * 128 + r0) * DD + cs;
    const unsigned short* gB1h = eh + (size_t)(kb * 128 + r1) * DD + cs;
    const unsigned short* gB0l = el + (size_t)(kb * 128 + r0) * DD + cs;
    const unsigned short* gB1l = el + (size_t)(kb * 128 + r1) * DD + cs;

    f4acc acc[4][4];
    #pragma unroll
    for (int i = 0; i < 4; ++i)
        #pragma unroll
        for (int j = 0; j < 4; ++j) acc[i][j] = (f4acc){0.f, 0.f, 0.f, 0.f};

    for (int ch = 0; ch < 8; ++ch) {
        const int kk = ch * 32;
        GLD16(gA0h + kk, Ah + n0 * 512);
        GLD16(gA1h + kk, Ah + n1 * 512);
        GLD16(gA0l + kk, Al + n0 * 512);
        GLD16(gA1l + kk, Al + n1 * 512);
        GLD16(gB0h + kk, Bh + n0 * 512);
        GLD16(gB1h + kk, Bh + n1 * 512);
        GLD16(gB0l + kk, Bl + n0 * 512);
        GLD16(gB1l + kk, Bl + n1 * 512);
        __syncthreads();

        bfrag ah[4], al[4];
        #pragma unroll
        for (int i = 0; i < 4; ++i) {
            const int off = (qh + i * 16 + l15) * 32 + quad * 8;
            ah[i] = *(const bfrag*)(Ah + off);
            al[i] = *(const bfrag*)(Al + off);
        }
        #pragma unroll
        for (int j = 0; j < 4; ++j) {
            const int off = (kh + j * 16 + l15) * 32 + quad * 8;
            const bfrag bh = *(const bfrag*)(Bh + off);
            const bfrag bl = *(const bfrag*)(Bl + off);
            #pragma unroll
            for (int i = 0; i < 4; ++i) {
                acc[i][j] = __builtin_amdgcn_mfma_f32_16x16x32_bf16(ah[i], bh, acc[i][j], 0, 0, 0);
                acc[i][j] = __builtin_amdgcn_mfma_f32_16x16x32_bf16(ah[i], bl, acc[i][j], 0, 0, 0);
                acc[i][j] = __builtin_amdgcn_mfma_f32_16x16x32_bf16(al[i], bh, acc[i][j], 0, 0, 0);
            }
        }
        __syncthreads();
    }

    // epilogue: per-(q, 32-code-group) min.  group g = kb*4 + (kh/32) + jp
    float bfv[4];
    #pragma unroll
    for (int j = 0; j < 4; ++j) bfv[j] = Bf[kb * 128 + kh + j * 16 + l15];
    #pragma unroll
    for (int i = 0; i < 4; ++i) {
        #pragma unroll
        for (int reg = 0; reg < 4; ++reg) {
            const int q = qt * 128 + qh + i * 16 + quad * 4 + reg;
            const float af = Af[q];
            #pragma unroll
            for (int jp = 0; jp < 2; ++jp) {
                const float c0 = acc[i][2 * jp][reg];
                const float c1 = acc[i][2 * jp + 1][reg];
                const float d0 = (af + bfv[2 * jp]) - (c0 + c0);
                const float d1 = (af + bfv[2 * jp + 1]) - (c1 + c1);
                float v = fminf(d0, d1);
                #pragma unroll
                for (int off = 1; off < 16; off <<= 1) v = fminf(v, __shfl_xor(v, off));
                if (l15 == 0)
                    tmp_min[(size_t)q * 256 + kb * 4 + (w >> 1) * 2 + jp] = v;
            }
        }
    }
}

// ---- K2: thr[q] = min_g + MU; init winner ----
__global__ __launch_bounds__(256) void thr_kernel(const float* __restrict__ tmp_min,
                                                  float* __restrict__ thr,
                                                  unsigned long long* __restrict__ winner) {
    const int q = blockIdx.x * 256 + threadIdx.x;
    const f4* p = (const f4*)(tmp_min + (size_t)q * 256);
    float m = 3.0e38f;
    #pragma unroll 8
    for (int i = 0; i < 64; ++i) {
        const f4 v = p[i];
        m = fminf(m, fminf(fminf(v.x, v.y), fminf(v.z, v.w)));
    }
    thr[q] = m + MU;
    winner[q] = ~0ULL;
}

// ---- K3a: compact qualifying (q, 32-code-group) pairs ----
__global__ __launch_bounds__(256) void compact_kernel(const float* __restrict__ tmp_min,
                                                      const float* __restrict__ thr,
                                                      int* __restrict__ list,
                                                      int* __restrict__ cnt) {
    const int id = blockIdx.x * 256 + threadIdx.x;   // 8.4M pairs
    if (tmp_min[id] <= thr[id >> 8]) {
        const int pos = atomicAdd(cnt, 1);
        if (pos < LIST_CAP) list[pos] = id;
    }
}

// ---- K3b: exact re-rank. Half-wave per item: 32 codes, z via LDS broadcast
// from zt (coalesced), e rows contiguous f4 (L1-resident). Bit-exact chain. ----
__global__ __launch_bounds__(256) void rescan2_kernel(
    const float* __restrict__ zt, const float* __restrict__ emb,
    const float* __restrict__ Af, const float* __restrict__ Bf,
    const int* __restrict__ list, const int* __restrict__ cnt,
    unsigned long long* __restrict__ winner) {
    __shared__ float zbuf[8][256];
    const int tid = threadIdx.x, lane = tid & 63, w = tid >> 6;
    const int half = lane >> 5, l32 = lane & 31;
    const int slot = blockIdx.x * 8 + w * 2 + half;
    const int slots = gridDim.x * 8;
    const int n = *cnt;
    f4* zb = (f4*)&zbuf[w * 2 + half][0];
    for (int it = slot; it < n; it += slots) {
        const int id = list[it];
        const int q = id >> 8, g = id & 255;
        const f4* zsrc = (const f4*)(zt + (size_t)q * DD);
        zb[l32]      = zsrc[l32];
        zb[l32 + 32] = zsrc[l32 + 32];
        const int k = g * 32 + l32;
        const f4* e = (const f4*)(emb + (size_t)k * DD);
        float c = 0.0f;
        #pragma unroll 8
        for (int i = 0; i < 64; ++i) {
            const f4 ev = e[i];
            const f4 zv = zb[i];
            c = __fmaf_rn(zv.x, ev.x, c);
            c = __fmaf_rn(zv.y, ev.y, c);
            c = __fmaf_rn(zv.z, ev.z, c);
            c = __fmaf_rn(zv.w, ev.w, c);
        }
        float bv = __fsub_rn(__fadd_rn(Af[q], Bf[k]), __fadd_rn(c, c));
        int bk = k;
        #pragma unroll
        for (int off = 1; off < 32; off <<= 1) {
            const float ob = __shfl_xor(bv, off);
            const int   ok = __shfl_xor(bk, off);
            if (ob < bv || (ob == bv && ok < bk)) { bv = ob; bk = ok; }
        }
        if (l32 == 0)
            atomicMin(winner + q,
                      (((unsigned long long)__float_as_uint(bv)) << 32) | (unsigned)bk);
    }
}

// ---- K4: finalize idx + loss ----
__global__ __launch_bounds__(256) void final_kernel(
    const unsigned long long* __restrict__ winner, float* __restrict__ out_idx,
    int* __restrict__ idx_i, double* __restrict__ loss_acc) {
    __shared__ double ls[4];
    const int tid = threadIdx.x, lane = tid & 63, w = tid >> 6;
    const int q = blockIdx.x * 256 + tid;
    const unsigned long long wv = winner[q];
    const int k = (int)(wv & 0xFFFFFFFFu);
    idx_i[q] = k;
    out_idx[q] = (float)k;
    double s = (double)__uint_as_float((unsigned)(wv >> 32));
    #pragma unroll
    for (int off = 1; off < 64; off <<= 1) s += __shfl_xor(s, off);
    if (lane == 0) ls[w] = s;
    __syncthreads();
    if (tid == 0) atomicAdd(loss_acc, ls[0] + ls[1] + ls[2] + ls[3]);
}

// ================== r5 fallback scorer (ws too small) ==================
__device__ __forceinline__ void ldstage(const float* __restrict__ emb, int st,
                                        int c, int p, f4* g) {
    const int kt = st >> 4, dc = st & 15;
    const float* src = emb + (((size_t)(kt * 512 + p * 128 + c)) << 8) + dc * 16;
    #pragma unroll
    for (int m = 0; m < 4; ++m) g[m] = *(const f4*)(src + 4 * m);
    const float* src2 = src + (64 << 8);
    #pragma unroll
    for (int m = 0; m < 4; ++m) g[4 + m] = *(const f4*)(src2 + 4 * m);
}

__global__ __launch_bounds__(256, 2) void score5_kernel(
    const float* __restrict__ z_e, const float* __restrict__ emb,
    const float* __restrict__ Bf, const float* __restrict__ Af,
    float* __restrict__ out_idx, int* __restrict__ idx_i,
    double* __restrict__ loss_acc) {
    __shared__ float zl[32 * 260];
    __shared__ float etp[64 * 132];
    const int tid = threadIdx.x;
    const int lane = tid & 63;
    const int w = tid >> 6;
    const int n0 = blockIdx.x * 32;
    const int b = n0 >> 10, t0 = n0 & 1023;
    {
        const int q = tid & 31;
        for (int d = tid >> 5; d < DD; d += 8)
            zl[q * 260 + d] = z_e[((size_t)(b * DD + d) << 10) + t0 + q];
    }
    float Aq[8];
    #pragma unroll
    for (int j = 0; j < 8; ++j) Aq[j] = Af[n0 + w * 8 + j];
    float best[8];
    int bidx[8];
    #pragma unroll
    for (int j = 0; j < 8; ++j) { best[j] = 3.0e38f; bidx[j] = 0; }
    f4 g[8];
    ldstage(emb, 0, lane, w, g);
    for (int kt = 0; kt < 16; ++kt) {
        f2 acc[8][4];
        #pragma unroll
        for (int j = 0; j < 8; ++j)
            #pragma unroll
            for (int p2 = 0; p2 < 4; ++p2) acc[j][p2] = (f2){0.0f, 0.0f};
        for (int dc = 0; dc < 16; ++dc) {
            __syncthreads();
            {
                float* dst = etp + lane * 132 + w * 32;
                #pragma unroll
                for (int m = 0; m < 4; ++m) {
                    const f4 a = g[m], bv = g[4 + m];
                    *(f4*)(dst + 8 * m)     = __builtin_shufflevector(a, bv, 0, 4, 1, 5);
                    *(f4*)(dst + 8 * m + 4) = __builtin_shufflevector(a, bv, 2, 6, 3, 7);
                }
            }
            __syncthreads();
            const int st = kt * 16 + dc;
            ldstage(emb, st < 255 ? st + 1 : 255, lane, w, g);
            #pragma unroll
            for (int s4 = 0; s4 < 4; ++s4) {
                const int dd0 = s4 * 4;
                f4 zv[8];
                #pragma unroll
                for (int j = 0; j < 8; ++j)
                    zv[j] = *(const f4*)(zl + (w * 8 + j) * 260 + dc * 16 + dd0);
                f4 ev[4][2];
                #pragma unroll
                for (int p2 = 0; p2 < 4; ++p2) {
                    const float* eb = etp + lane * 132 + p2 * 32 + dd0 * 2;
                    ev[p2][0] = *(const f4*)(eb);
                    ev[p2][1] = *(const f4*)(eb + 4);
                }
                #pragma unroll
                for (int j = 0; j < 8; ++j) {
                    #pragma unroll
                    for (int dd = 0; dd < 4; ++dd) {
                        const float zs = zv[j][dd];
                        const f2 z2 = {zs, zs};
                        #pragma unroll
                        for (int p2 = 0; p2 < 4; ++p2) {
                            const f4 evv = ev[p2][dd >> 1];
                            const f2 e2 = (dd & 1)
                                ? __builtin_shufflevector(evv, evv, 2, 3)
                                : __builtin_shufflevector(evv, evv, 0, 1);
                            acc[j][p2] = PKFMA(z2, e2, acc[j][p2]);
                        }
                    }
                }
            }
        }
        const int kt0 = kt * 512;
        float Bk[8];
        #pragma unroll
        for (int i = 0; i < 8; ++i) Bk[i] = Bf[kt0 + 64 * i + lane];
        #pragma unroll
        for (int p2 = 0; p2 < 4; ++p2) {
            #pragma unroll
            for (int s = 0; s < 2; ++s) {
                const int i = 2 * p2 + s;
                #pragma unroll
                for (int j = 0; j < 8; ++j) {
                    const float C = s ? acc[j][p2].y : acc[j][p2].x;
                    const float dist = __fsub_rn(__fadd_rn(Aq[j], Bk[i]), __fadd_rn(C, C));
                    const int k = kt0 + 64 * i + lane;
                    if (dist < best[j]) { best[j] = dist; bidx[j] = k; }
                }
            }
        }
    }
    #pragma unroll
    for (int j = 0; j < 8; ++j) {
        float bb = best[j];
        int bi = bidx[j];
        #pragma unroll
        for (int off = 1; off < 64; off <<= 1) {
            const float ob = __shfl_xor(bb, off);
            const int oi = __shfl_xor(bi, off);
            if (ob < bb || (ob == bb && oi < bi)) { bb = ob; bi = oi; }
        }
        best[j] = bb; bidx[j] = bi;
    }
    if (lane == 0) {
        double lp = 0.0;
        #pragma unroll
        for (int j = 0; j < 8; ++j) {
            const int n = n0 + w * 8 + j;
            out_idx[n] = (float)bidx[j];
            idx_i[n] = bidx[j];
            lp += (double)best[j];
        }
        atomicAdd(loss_acc, lp);
    }
}

// ================== shared epilogue kernels ==================
__global__ __launch_bounds__(256) void gather_kernel(const float* __restrict__ emb,
                                                     const int* __restrict__ idx_i,
                                                     float* __restrict__ zq) {
    const int blk = blockIdx.x;
    const int b = blk >> 4;
    const int t0 = (blk & 15) * 64;
    const int q = threadIdx.x & 63;
    const int dc = threadIdx.x >> 6;
    const int n = b * TT + t0 + q;
    const int k = idx_i[n];
    const f4* erow = (const f4*)(emb + (size_t)k * DD + dc * 64);
    #pragma unroll
    for (int jj = 0; jj < 16; ++jj) {
        const f4 v = erow[jj];
        const int d = dc * 64 + jj * 4;
        zq[(size_t)(b * DD + d + 0) * TT + t0 + q] = v.x;
        zq[(size_t)(b * DD + d + 1) * TT + t0 + q] = v.y;
        zq[(size_t)(b * DD + d + 2) * TT + t0 + q] = v.z;
        zq[(size_t)(b * DD + d + 3) * TT + t0 + q] = v.w;
    }
}

__global__ void fin_kernel(const double* __restrict__ loss_acc,
                           float* __restrict__ out_loss) {
    out_loss[0] = (float)(loss_acc[0] * (1.0 / ((double)BB * DD * TT)));
}

extern "C" void kernel_launch(void* const* d_in, const int* in_sizes, int n_in,
                              void* d_out, int out_size, void* d_ws, size_t ws_size,
                              hipStream_t stream) {
    const float* z_e = (const float*)d_in[0];
    const float* emb = (const float*)d_in[1];

    float* out      = (float*)d_out;
    float* zq       = out;
    float* out_loss = out + (size_t)BB * DD * TT;
    float* out_idx  = out_loss + 1;

    char* ws = (char*)d_ws;
    double* loss_acc = (double*)(ws + WS_LOSS);
    float*  Bf       = (float*)(ws + WS_BF);
    float*  Af       = (float*)(ws + WS_AF);
    int*    idx_i    = (int*)(ws + WS_IDX);

    hipMemsetAsync(d_ws, 0, 64, stream);
    bsum_kernel<<<KK / 256, 256, 0, stream>>>(emb, Bf);
    asum_kernel<<<(BB * TT) / 256, 256, 0, stream>>>(z_e, Af);

    if (ws_size >= (size_t)WS_NEED) {
        int*    cnt     = (int*)(ws + WS_CNT);
        float*  thr     = (float*)(ws + WS_THR);
        unsigned long long* winner = (unsigned long long*)(ws + WS_WIN);
        float*  zt      = (float*)(ws + WS_ZT);
        float*  tmp_min = (float*)(ws + WS_TMIN);
        int*    list    = (int*)(ws + WS_LIST);
        unsigned short* zh = (unsigned short*)(ws + WS_ZH);
        unsigned short* zl = (unsigned short*)(ws + WS_ZL);
        unsigned short* eh = (unsigned short*)(ws + WS_EH);
        unsigned short* el = (unsigned short*)(ws + WS_EL);

        ztrans_kernel<<<(BB * TT / 64) * 4, 256, 0, stream>>>(z_e, zt);
        splitz_kernel<<<(BB * TT) / 64, 256, 0, stream>>>(z_e, zh, zl);
        splite_kernel<<<(KK * DD) / 1024, 256, 0, stream>>>(emb, eh, el);
        mfma_score_kernel<<<(BB * TT / 128) * 64, 256, 0, stream>>>(zh, zl, eh, el, Af, Bf, tmp_min);
        thr_kernel<<<(BB * TT) / 256, 256, 0, stream>>>(tmp_min, thr, winner);
        compact_kernel<<<(BB * TT * 256) / 256, 256, 0, stream>>>(tmp_min, thr, list, cnt);
        rescan2_kernel<<<512, 256, 0, stream>>>(zt, emb, Af, Bf, list, cnt, winner);
        final_kernel<<<(BB * TT) / 256, 256, 0, stream>>>(winner, out_idx, idx_i, loss_acc);
    } else {
        score5_kernel<<<(BB * TT) / 32, 256, 0, stream>>>(z_e, emb, Bf, Af, out_idx, idx_i, loss_acc);
    }

    gather_kernel<<<(BB * TT) / 64, 256, 0, stream>>>(emb, idx_i, zq);
    fin_kernel<<<1, 1, 0, stream>>>(loss_acc, out_loss);
}

// Round 8
// 849.471 us; speedup vs baseline: 9.3983x; 1.5771x over previous
//
#include <hip/hip_runtime.h>
#include <stdint.h>

#define BB 32
#define DD 256
#define TT 1024
#define KK 8192

typedef __attribute__((ext_vector_type(2))) float f2;
typedef __attribute__((ext_vector_type(4))) float f4;
typedef __attribute__((ext_vector_type(8))) short bfrag;   // 8 bf16 = 4 VGPR
typedef __attribute__((ext_vector_type(4))) float f4acc;   // MFMA acc

#if __has_builtin(__builtin_elementwise_fma)
#define PKFMA(a, b, c) __builtin_elementwise_fma(a, b, c)
#else
static __device__ __forceinline__ f2 pkfma_(f2 a, f2 b, f2 c) {
    f2 r; r.x = __fmaf_rn(a.x, b.x, c.x); r.y = __fmaf_rn(a.y, b.y, c.y); return r;
}
#define PKFMA(a, b, c) pkfma_(a, b, c)
#endif

#define GLD16(gp, lp)                                                          \
    __builtin_amdgcn_global_load_lds(                                          \
        (const __attribute__((address_space(1))) uint32_t*)(gp),               \
        (__attribute__((address_space(3))) uint32_t*)(lp), 16, 0, 0)

#define MU 3.0e-4f
#define BCAP 4096
#define LIST_CAP 1048576

// ---------------- fast-path ws layout (bytes) ----------------
#define WS_LOSS   0            // double
#define WS_CNT    8            // int (overflow count)
#define WS_BCNT   16           // int[256]
#define WS_BF     1088
#define WS_AF     33856
#define WS_IDX    164928
#define WS_WIN    296000
#define WS_ZT     558144
#define WS_TMIN   34112576
#define WS_BKT    67667008
#define WS_LIST   71861312
#define WS_ZH     76055616
#define WS_ZL     92832832
#define WS_EH     109610048
#define WS_NEED   113804352

__device__ __forceinline__ unsigned short bf16_rne(float x) {
    uint32_t u = __float_as_uint(x);
    uint32_t r = (u + 0x7FFFu + ((u >> 16) & 1u)) >> 16;
    return (unsigned short)r;
}
__device__ __forceinline__ float bf16_to_f(unsigned short h) {
    return __uint_as_float(((uint32_t)h) << 16);
}

// Bit-exact numpy pairwise_sum of x[i]^2, n=256.
__device__ __forceinline__ float np_sq_sum256(const float* __restrict__ base, int stride) {
    float res[2];
    #pragma unroll
    for (int blk = 0; blk < 2; ++blk) {
        const int o = blk * 128;
        float r[8];
        #pragma unroll
        for (int j = 0; j < 8; ++j) {
            const float x = base[(o + j) * stride];
            r[j] = __fmul_rn(x, x);
        }
        for (int i = 8; i < 128; i += 8) {
            #pragma unroll
            for (int j = 0; j < 8; ++j) {
                const float x = base[(o + i + j) * stride];
                r[j] = __fadd_rn(r[j], __fmul_rn(x, x));
            }
        }
        res[blk] = __fadd_rn(__fadd_rn(__fadd_rn(r[0], r[1]), __fadd_rn(r[2], r[3])),
                             __fadd_rn(__fadd_rn(r[4], r[5]), __fadd_rn(r[6], r[7])));
    }
    return __fadd_rn(res[0], res[1]);
}

__global__ __launch_bounds__(256) void bsum_kernel(const float* __restrict__ emb,
                                                   float* __restrict__ Bf) {
    const int k = blockIdx.x * 256 + threadIdx.x;
    Bf[k] = np_sq_sum256(emb + (size_t)k * DD, 1);
}

__global__ __launch_bounds__(256) void asum_kernel(const float* __restrict__ z_e,
                                                   float* __restrict__ Af) {
    const int n = blockIdx.x * 256 + threadIdx.x;
    const int b = n >> 10, t = n & 1023;
    Af[n] = np_sq_sum256(z_e + ((size_t)b << 18) + t, TT);
}

// ---- fused z prep: zt (fp32 [q][d]) + zh/zl (bf16 split) + Af, one pass ----
__global__ __launch_bounds__(256) void fusedz_kernel(const float* __restrict__ z_e,
                                                     float* __restrict__ zt,
                                                     unsigned short* __restrict__ zh,
                                                     unsigned short* __restrict__ zl,
                                                     float* __restrict__ Af) {
    __shared__ float tile[64 * 261];
    const int tid = threadIdx.x, l = tid & 63, r = tid >> 6;
    const int n0 = blockIdx.x * 64;           // 512 blocks
    const int b = n0 >> 10, t0 = n0 & 1023;
    for (int d = r; d < DD; d += 4)
        tile[l * 261 + d] = z_e[(size_t)(b * DD + d) * TT + t0 + l];
    __syncthreads();
    const int q = tid >> 2, c0 = (tid & 3) * 64;
    const float* src = &tile[q * 261 + c0];
    float* dzt = zt + (size_t)(n0 + q) * DD + c0;
    unsigned short* dzh = zh + (size_t)(n0 + q) * DD + c0;
    unsigned short* dzl = zl + (size_t)(n0 + q) * DD + c0;
    #pragma unroll
    for (int i = 0; i < 16; ++i) {
        f4 v;
        v.x = src[4 * i + 0]; v.y = src[4 * i + 1];
        v.z = src[4 * i + 2]; v.w = src[4 * i + 3];
        *(f4*)(dzt + 4 * i) = v;
        ushort4 h, lo;
        h.x = bf16_rne(v.x); lo.x = bf16_rne(__fsub_rn(v.x, bf16_to_f(h.x)));
        h.y = bf16_rne(v.y); lo.y = bf16_rne(__fsub_rn(v.y, bf16_to_f(h.y)));
        h.z = bf16_rne(v.z); lo.z = bf16_rne(__fsub_rn(v.z, bf16_to_f(h.z)));
        h.w = bf16_rne(v.w); lo.w = bf16_rne(__fsub_rn(v.w, bf16_to_f(h.w)));
        *(ushort4*)(dzh + 4 * i) = h;
        *(ushort4*)(dzl + 4 * i) = lo;
    }
    if (tid < 64) Af[n0 + tid] = np_sq_sum256(&tile[tid * 261], 1);
}

// ---- split e into bf16 hi only ----
__global__ __launch_bounds__(256) void splite_kernel(const float* __restrict__ emb,
                                                     unsigned short* __restrict__ eh) {
    const int i0 = (blockIdx.x * 256 + threadIdx.x) * 4;
    const f4 v = *(const f4*)(emb + i0);
    ushort4 h;
    h.x = bf16_rne(v.x); h.y = bf16_rne(v.y); h.z = bf16_rne(v.z); h.w = bf16_rne(v.w);
    *(ushort4*)(eh + i0) = h;
}

// ---- K1: 2-term split-bf16 MFMA scorer (zh*eh + zl*eh); per-(q,32-group) min ----
__global__ __launch_bounds__(256) void mfma2_kernel(
    const unsigned short* __restrict__ zh, const unsigned short* __restrict__ zl,
    const unsigned short* __restrict__ eh,
    const float* __restrict__ Af, const float* __restrict__ Bf,
    float* __restrict__ tmp_min) {
    __shared__ unsigned short Ah[4096], Al[4096], Bh[4096];  // [128][32], 24 KiB

    const int tid  = threadIdx.x;
    const int lane = tid & 63;
    const int w    = tid >> 6;
    const int quad = lane >> 4;
    const int l15  = lane & 15;
    const int qt   = blockIdx.x >> 6;
    const int kb   = blockIdx.x & 63;
    const int qh   = (w & 1) * 64;
    const int kh   = (w >> 1) * 64;

    const int n0 = w * 2, n1 = n0 + 1;
    const int r0 = 16 * n0 + (lane >> 2), r1 = 16 * n1 + (lane >> 2);
    const int cs = (lane & 3) * 8;
    const unsigned short* gA0h = zh + (size_t)(qt * 128 + r0) * DD + cs;
    const unsigned short* gA1h = zh + (size_t)(qt * 128 + r1) * DD + cs;
    const unsigned short* gA0l = zl + (size_t)(qt * 128 + r0) * DD + cs;
    const unsigned short* gA1l = zl + (size_t)(qt * 128 + r1) * DD + cs;
    const unsigned short* gB0h = eh + (size_t)(kb * 128 + r0) * DD + cs;
    const unsigned short* gB1h = eh + (size_t)(kb * 128 + r1) * DD + cs;

    f4acc acc[4][4];
    #pragma unroll
    for (int i = 0; i < 4; ++i)
        #pragma unroll
        for (int j = 0; j < 4; ++j) acc[i][j] = (f4acc){0.f, 0.f, 0.f, 0.f};

    for (int ch = 0; ch < 8; ++ch) {
        const int kk = ch * 32;
        GLD16(gA0h + kk, Ah + n0 * 512);
        GLD16(gA1h + kk, Ah + n1 * 512);
        GLD16(gA0l + kk, Al + n0 * 512);
        GLD16(gA1l + kk, Al + n1 * 512);
        GLD16(gB0h + kk, Bh + n0 * 512);
        GLD16(gB1h + kk, Bh + n1 * 512);
        __syncthreads();

        bfrag ah[4], al[4];
        #pragma unroll
        for (int i = 0; i < 4; ++i) {
            const int off = (qh + i * 16 + l15) * 32 + quad * 8;
            ah[i] = *(const bfrag*)(Ah + off);
            al[i] = *(const bfrag*)(Al + off);
        }
        #pragma unroll
        for (int j = 0; j < 4; ++j) {
            const int off = (kh + j * 16 + l15) * 32 + quad * 8;
            const bfrag bh = *(const bfrag*)(Bh + off);
            #pragma unroll
            for (int i = 0; i < 4; ++i) {
                acc[i][j] = __builtin_amdgcn_mfma_f32_16x16x32_bf16(ah[i], bh, acc[i][j], 0, 0, 0);
                acc[i][j] = __builtin_amdgcn_mfma_f32_16x16x32_bf16(al[i], bh, acc[i][j], 0, 0, 0);
            }
        }
        __syncthreads();
    }

    // epilogue: per-(q, 32-code-group) min. group g = kb*4 + (kh/32) + jp
    float bfv[4];
    #pragma unroll
    for (int j = 0; j < 4; ++j) bfv[j] = Bf[kb * 128 + kh + j * 16 + l15];
    #pragma unroll
    for (int i = 0; i < 4; ++i) {
        #pragma unroll
        for (int reg = 0; reg < 4; ++reg) {
            const int q = qt * 128 + qh + i * 16 + quad * 4 + reg;
            const float af = Af[q];
            #pragma unroll
            for (int jp = 0; jp < 2; ++jp) {
                const float c0 = acc[i][2 * jp][reg];
                const float c1 = acc[i][2 * jp + 1][reg];
                const float d0 = (af + bfv[2 * jp]) - (c0 + c0);
                const float d1 = (af + bfv[2 * jp + 1]) - (c1 + c1);
                float v = fminf(d0, d1);
                #pragma unroll
                for (int off = 1; off < 16; off <<= 1) v = fminf(v, __shfl_xor(v, off));
                if (l15 == 0)
                    tmp_min[(size_t)q * 256 + kb * 4 + (w >> 1) * 2 + jp] = v;
            }
        }
    }
}

// ---- K2: fused select: per-q min+thr, winner init, bucket scatter ----
__global__ __launch_bounds__(256) void select_kernel(
    const float* __restrict__ tmp_min, int* __restrict__ bcnt,
    int* __restrict__ bucket, int* __restrict__ list, int* __restrict__ cnt,
    unsigned long long* __restrict__ winner) {
    const int tid = threadIdx.x, lane = tid & 63, w = tid >> 6;
    const int q = blockIdx.x * 4 + w;          // 8192 blocks
    const f4 v = *(const f4*)(tmp_min + (size_t)q * 256 + lane * 4);
    float m = fminf(fminf(v.x, v.y), fminf(v.z, v.w));
    #pragma unroll
    for (int off = 1; off < 64; off <<= 1) m = fminf(m, __shfl_xor(m, off));
    const float thr = m + MU;
    if (lane == 0) winner[q] = ~0ULL;
    float vv[4] = {v.x, v.y, v.z, v.w};
    #pragma unroll
    for (int j = 0; j < 4; ++j) {
        if (vv[j] <= thr) {
            const int g = lane * 4 + j;
            const int pos = atomicAdd(&bcnt[g], 1);
            if (pos < BCAP) bucket[g * BCAP + pos] = q;
            else {
                const int op = atomicAdd(cnt, 1);
                if (op < LIST_CAP) list[op] = (q << 8) | g;
            }
        }
    }
}

// ---- K3: bucketed exact re-rank: block per 32-code group, e staged once ----
__global__ __launch_bounds__(256) void rescan_bucket_kernel(
    const float* __restrict__ zt, const float* __restrict__ emb,
    const float* __restrict__ Af, const float* __restrict__ Bf,
    const int* __restrict__ bcnt, const int* __restrict__ bucket,
    unsigned long long* __restrict__ winner) {
    __shared__ float elds[256 * 33];   // [d][k], stride 33 -> conflict-free
    __shared__ float zbuf[8][256];
    __shared__ float bfs[32];
    const int g = blockIdx.x;          // 256 groups
    const int tid = threadIdx.x, lane = tid & 63, w = tid >> 6;
    const int half = lane >> 5, l32 = lane & 31, slot = w * 2 + half;
    {   // stage e rows (coalesced reads, transpose into [d][k])
        const int k = tid >> 3, s0 = (tid & 7) * 32;
        const float* src = emb + (size_t)(g * 32 + k) * DD + s0;
        #pragma unroll
        for (int i = 0; i < 8; ++i) {
            const f4 v = *(const f4*)(src + i * 4);
            elds[(s0 + 4 * i + 0) * 33 + k] = v.x;
            elds[(s0 + 4 * i + 1) * 33 + k] = v.y;
            elds[(s0 + 4 * i + 2) * 33 + k] = v.z;
            elds[(s0 + 4 * i + 3) * 33 + k] = v.w;
        }
        if (tid < 32) bfs[tid] = Bf[g * 32 + tid];
    }
    __syncthreads();
    const int nit = min(bcnt[g], BCAP);
    const int kme = g * 32 + l32;
    for (int base = 0; base < nit; base += 8) {
        const int it = base + slot;
        int q = -1;
        if (it < nit) {
            q = bucket[g * BCAP + it];
            f4* zb = (f4*)&zbuf[slot][0];
            const f4* zsrc = (const f4*)(zt + (size_t)q * DD);
            zb[l32]      = zsrc[l32];
            zb[l32 + 32] = zsrc[l32 + 32];
        }
        __syncthreads();
        if (it < nit) {
            const float* zp = &zbuf[slot][0];
            float c = 0.0f;
            #pragma unroll 8
            for (int d = 0; d < DD; ++d)
                c = __fmaf_rn(zp[d], elds[d * 33 + l32], c);
            float bv = __fsub_rn(__fadd_rn(Af[q], bfs[l32]), __fadd_rn(c, c));
            int bk = kme;
            #pragma unroll
            for (int off = 1; off < 32; off <<= 1) {
                const float ob = __shfl_xor(bv, off);
                const int   ok = __shfl_xor(bk, off);
                if (ob < bv || (ob == bv && ok < bk)) { bv = ob; bk = ok; }
            }
            if (l32 == 0)
                atomicMin(winner + q,
                          (((unsigned long long)__float_as_uint(bv)) << 32) | (unsigned)bk);
        }
        __syncthreads();
    }
}

// ---- K3x: overflow re-rank (per-item, rare) ----
__global__ __launch_bounds__(256) void rescan2_kernel(
    const float* __restrict__ zt, const float* __restrict__ emb,
    const float* __restrict__ Af, const float* __restrict__ Bf,
    const int* __restrict__ list, const int* __restrict__ cnt,
    unsigned long long* __restrict__ winner) {
    __shared__ float zbuf[8][256];
    const int tid = threadIdx.x, lane = tid & 63, w = tid >> 6;
    const int half = lane >> 5, l32 = lane & 31;
    const int slot = blockIdx.x * 8 + w * 2 + half;
    const int slots = gridDim.x * 8;
    const int n = min(*cnt, LIST_CAP);
    f4* zb = (f4*)&zbuf[w * 2 + half][0];
    for (int it = slot; it < n; it += slots) {
        const int id = list[it];
        const int q = id >> 8, g = id & 255;
        const f4* zsrc = (const f4*)(zt + (size_t)q * DD);
        zb[l32]      = zsrc[l32];
        zb[l32 + 32] = zsrc[l32 + 32];
        const int k = g * 32 + l32;
        const f4* e = (const f4*)(emb + (size_t)k * DD);
        float c = 0.0f;
        #pragma unroll 8
        for (int i = 0; i < 64; ++i) {
            const f4 ev = e[i];
            const f4 zv = zb[i];
            c = __fmaf_rn(zv.x, ev.x, c);
            c = __fmaf_rn(zv.y, ev.y, c);
            c = __fmaf_rn(zv.z, ev.z, c);
            c = __fmaf_rn(zv.w, ev.w, c);
        }
        float bv = __fsub_rn(__fadd_rn(Af[q], Bf[k]), __fadd_rn(c, c));
        int bk = k;
        #pragma unroll
        for (int off = 1; off < 32; off <<= 1) {
            const float ob = __shfl_xor(bv, off);
            const int   ok = __shfl_xor(bk, off);
            if (ob < bv || (ob == bv && ok < bk)) { bv = ob; bk = ok; }
        }
        if (l32 == 0)
            atomicMin(winner + q,
                      (((unsigned long long)__float_as_uint(bv)) << 32) | (unsigned)bk);
    }
}

// ---- K4: finalize idx + loss ----
__global__ __launch_bounds__(256) void final_kernel(
    const unsigned long long* __restrict__ winner, float* __restrict__ out_idx,
    int* __restrict__ idx_i, double* __restrict__ loss_acc) {
    __shared__ double ls[4];
    const int tid = threadIdx.x, lane = tid & 63, w = tid >> 6;
    const int q = blockIdx.x * 256 + tid;
    const unsigned long long wv = winner[q];
    const int k = (int)(wv & 0xFFFFFFFFu);
    idx_i[q] = k;
    out_idx[q] = (float)k;
    double s = (double)__uint_as_float((unsigned)(wv >> 32));
    #pragma unroll
    for (int off = 1; off < 64; off <<= 1) s += __shfl_xor(s, off);
    if (lane == 0) ls[w] = s;
    __syncthreads();
    if (tid == 0) atomicAdd(loss_acc, ls[0] + ls[1] + ls[2] + ls[3]);
}

// ================== r5 fallback scorer (ws too small) ==================
__device__ __forceinline__ void ldstage(const float* __restrict__ emb, int st,
                                        int c, int p, f4* g) {
    const int kt = st >> 4, dc = st & 15;
    const float* src = emb + (((size_t)(kt * 512 + p * 128 + c)) << 8) + dc * 16;
    #pragma unroll
    for (int m = 0; m < 4; ++m) g[m] = *(const f4*)(src + 4 * m);
    const float* src2 = src + (64 << 8);
    #pragma unroll
    for (int m = 0; m < 4; ++m) g[4 + m] = *(const f4*)(src2 + 4 * m);
}

__global__ __launch_bounds__(256, 2) void score5_kernel(
    const float* __restrict__ z_e, const float* __restrict__ emb,
    const float* __restrict__ Bf, const float* __restrict__ Af,
    float* __restrict__ out_idx, int* __restrict__ idx_i,
    double* __restrict__ loss_acc) {
    __shared__ float zl[32 * 260];
    __shared__ float etp[64 * 132];
    const int tid = threadIdx.x;
    const int lane = tid & 63;
    const int w = tid >> 6;
    const int n0 = blockIdx.x * 32;
    const int b = n0 >> 10, t0 = n0 & 1023;
    {
        const int q = tid & 31;
        for (int d = tid >> 5; d < DD; d += 8)
            zl[q * 260 + d] = z_e[((size_t)(b * DD + d) << 10) + t0 + q];
    }
    float Aq[8];
    #pragma unroll
    for (int j = 0; j < 8; ++j) Aq[j] = Af[n0 + w * 8 + j];
    float best[8];
    int bidx[8];
    #pragma unroll
    for (int j = 0; j < 8; ++j) { best[j] = 3.0e38f; bidx[j] = 0; }
    f4 g[8];
    ldstage(emb, 0, lane, w, g);
    for (int kt = 0; kt < 16; ++kt) {
        f2 acc[8][4];
        #pragma unroll
        for (int j = 0; j < 8; ++j)
            #pragma unroll
            for (int p2 = 0; p2 < 4; ++p2) acc[j][p2] = (f2){0.0f, 0.0f};
        for (int dc = 0; dc < 16; ++dc) {
            __syncthreads();
            {
                float* dst = etp + lane * 132 + w * 32;
                #pragma unroll
                for (int m = 0; m < 4; ++m) {
                    const f4 a = g[m], bv = g[4 + m];
                    *(f4*)(dst + 8 * m)     = __builtin_shufflevector(a, bv, 0, 4, 1, 5);
                    *(f4*)(dst + 8 * m + 4) = __builtin_shufflevector(a, bv, 2, 6, 3, 7);
                }
            }
            __syncthreads();
            const int st = kt * 16 + dc;
            ldstage(emb, st < 255 ? st + 1 : 255, lane, w, g);
            #pragma unroll
            for (int s4 = 0; s4 < 4; ++s4) {
                const int dd0 = s4 * 4;
                f4 zv[8];
                #pragma unroll
                for (int j = 0; j < 8; ++j)
                    zv[j] = *(const f4*)(zl + (w * 8 + j) * 260 + dc * 16 + dd0);
                f4 ev[4][2];
                #pragma unroll
                for (int p2 = 0; p2 < 4; ++p2) {
                    const float* eb = etp + lane * 132 + p2 * 32 + dd0 * 2;
                    ev[p2][0] = *(const f4*)(eb);
                    ev[p2][1] = *(const f4*)(eb + 4);
                }
                #pragma unroll
                for (int j = 0; j < 8; ++j) {
                    #pragma unroll
                    for (int dd = 0; dd < 4; ++dd) {
                        const float zs = zv[j][dd];
                        const f2 z2 = {zs, zs};
                        #pragma unroll
                        for (int p2 = 0; p2 < 4; ++p2) {
                            const f4 evv = ev[p2][dd >> 1];
                            const f2 e2 = (dd & 1)
                                ? __builtin_shufflevector(evv, evv, 2, 3)
                                : __builtin_shufflevector(evv, evv, 0, 1);
                            acc[j][p2] = PKFMA(z2, e2, acc[j][p2]);
                        }
                    }
                }
            }
        }
        const int kt0 = kt * 512;
        float Bk[8];
        #pragma unroll
        for (int i = 0; i < 8; ++i) Bk[i] = Bf[kt0 + 64 * i + lane];
        #pragma unroll
        for (int p2 = 0; p2 < 4; ++p2) {
            #pragma unroll
            for (int s = 0; s < 2; ++s) {
                const int i = 2 * p2 + s;
                #pragma unroll
                for (int j = 0; j < 8; ++j) {
                    const float C = s ? acc[j][p2].y : acc[j][p2].x;
                    const float dist = __fsub_rn(__fadd_rn(Aq[j], Bk[i]), __fadd_rn(C, C));
                    const int k = kt0 + 64 * i + lane;
                    if (dist < best[j]) { best[j] = dist; bidx[j] = k; }
                }
            }
        }
    }
    #pragma unroll
    for (int j = 0; j < 8; ++j) {
        float bb = best[j];
        int bi = bidx[j];
        #pragma unroll
        for (int off = 1; off < 64; off <<= 1) {
            const float ob = __shfl_xor(bb, off);
            const int oi = __shfl_xor(bi, off);
            if (ob < bb || (ob == bb && oi < bi)) { bb = ob; bi = oi; }
        }
        best[j] = bb; bidx[j] = bi;
    }
    if (lane == 0) {
        double lp = 0.0;
        #pragma unroll
        for (int j = 0; j < 8; ++j) {
            const int n = n0 + w * 8 + j;
            out_idx[n] = (float)bidx[j];
            idx_i[n] = bidx[j];
            lp += (double)best[j];
        }
        atomicAdd(loss_acc, lp);
    }
}

// ================== shared epilogue kernels ==================
__global__ __launch_bounds__(256) void gather_kernel(const float* __restrict__ emb,
                                                     const int* __restrict__ idx_i,
                                                     float* __restrict__ zq) {
    const int blk = blockIdx.x;
    const int b = blk >> 4;
    const int t0 = (blk & 15) * 64;
    const int q = threadIdx.x & 63;
    const int dc = threadIdx.x >> 6;
    const int n = b * TT + t0 + q;
    const int k = idx_i[n];
    const f4* erow = (const f4*)(emb + (size_t)k * DD + dc * 64);
    #pragma unroll
    for (int jj = 0; jj < 16; ++jj) {
        const f4 v = erow[jj];
        const int d = dc * 64 + jj * 4;
        zq[(size_t)(b * DD + d + 0) * TT + t0 + q] = v.x;
        zq[(size_t)(b * DD + d + 1) * TT + t0 + q] = v.y;
        zq[(size_t)(b * DD + d + 2) * TT + t0 + q] = v.z;
        zq[(size_t)(b * DD + d + 3) * TT + t0 + q] = v.w;
    }
}

__global__ void fin_kernel(const double* __restrict__ loss_acc,
                           float* __restrict__ out_loss) {
    out_loss[0] = (float)(loss_acc[0] * (1.0 / ((double)BB * DD * TT)));
}

extern "C" void kernel_launch(void* const* d_in, const int* in_sizes, int n_in,
                              void* d_out, int out_size, void* d_ws, size_t ws_size,
                              hipStream_t stream) {
    const float* z_e = (const float*)d_in[0];
    const float* emb = (const float*)d_in[1];

    float* out      = (float*)d_out;
    float* zq       = out;
    float* out_loss = out + (size_t)BB * DD * TT;
    float* out_idx  = out_loss + 1;

    char* ws = (char*)d_ws;
    double* loss_acc = (double*)(ws + WS_LOSS);
    float*  Bf       = (float*)(ws + WS_BF);
    float*  Af       = (float*)(ws + WS_AF);
    int*    idx_i    = (int*)(ws + WS_IDX);

    hipMemsetAsync(d_ws, 0, 1088, stream);
    bsum_kernel<<<KK / 256, 256, 0, stream>>>(emb, Bf);

    if (ws_size >= (size_t)WS_NEED) {
        int*    cnt    = (int*)(ws + WS_CNT);
        int*    bcnt   = (int*)(ws + WS_BCNT);
        unsigned long long* winner = (unsigned long long*)(ws + WS_WIN);
        float*  zt     = (float*)(ws + WS_ZT);
        float*  tmp_min = (float*)(ws + WS_TMIN);
        int*    bucket = (int*)(ws + WS_BKT);
        int*    list   = (int*)(ws + WS_LIST);
        unsigned short* zh = (unsigned short*)(ws + WS_ZH);
        unsigned short* zl = (unsigned short*)(ws + WS_ZL);
        unsigned short* eh = (unsigned short*)(ws + WS_EH);

        fusedz_kernel<<<(BB * TT) / 64, 256, 0, stream>>>(z_e, zt, zh, zl, Af);
        splite_kernel<<<(KK * DD) / 1024, 256, 0, stream>>>(emb, eh);
        mfma2_kernel<<<(BB * TT / 128) * 64, 256, 0, stream>>>(zh, zl, eh, Af, Bf, tmp_min);
        select_kernel<<<(BB * TT) / 4, 256, 0, stream>>>(tmp_min, bcnt, bucket, list, cnt, winner);
        rescan_bucket_kernel<<<256, 256, 0, stream>>>(zt, emb, Af, Bf, bcnt, bucket, winner);
        rescan2_kernel<<<128, 256, 0, stream>>>(zt, emb, Af, Bf, list, cnt, winner);
        final_kernel<<<(BB * TT) / 256, 256, 0, stream>>>(winner, out_idx, idx_i, loss_acc);
    } else {
        asum_kernel<<<(BB * TT) / 256, 256, 0, stream>>>(z_e, Af);
        score5_kernel<<<(BB * TT) / 32, 256, 0, stream>>>(z_e, emb, Bf, Af, out_idx, idx_i, loss_acc);
    }

    gather_kernel<<<(BB * TT) / 64, 256, 0, stream>>>(emb, idx_i, zq);
    fin_kernel<<<1, 1, 0, stream>>>(loss_acc, out_loss);
}